// Round 18
// baseline (492.426 us; speedup 1.0000x reference)
//
#include <hip/hip_runtime.h>
#include <math.h>

// Problem constants
#define BBATCH 8
#define CC 96
#define HH 224
#define NHW 32            // 224/7 windows per side
#define NWIN 1024
#define TOPK 256
#define PERK 24
#define DST 16
#define DTR 6
#define LL 12544          // 256*49
#define LCP 52            // padded row length (49 used + 3 zero pad)
#define NG 13             // float4 groups per row
#define TCH 256           // one chunk = ONE scan window (49 steps)
#define NBK 32            // B*4 directions
#define XROW 1248         // xs floats per window: 24 x 52 (y reuses head: 1176)
#define WST4 2080         // bf16 stage floats per window: P 312 uint4 + Q 208 uint4
#define LOG2E 1.4426950408889634f

// fast hardware exp2: exactly one v_exp_f32
#define EXP2F(x) __builtin_amdgcn_exp2f(x)

// workspace offsets (floats) — total 34,374,912 floats = 137.5 MB (< proven 164.8)
#define OFF_POOL 0
#define OFF_LOG  786432
#define OFF_PROB 794624
#define OFF_RW   802816
#define OFF_RANK 804864
#define OFF_SEL  813056
#define OFF_WEFF 815104
#define OFF_CP   820480      // 3,145,728; reused as hin (read-before-write in carry)
#define OFF_CS   3966208     // 3,145,728
#define OFF_XSD  7111936     // 10,223,616: xs dense [8192][24][52]; y written into head
#define OFF_STG  17335552    // 8192*2080 = 17,039,360: bf16-packed stage

// DPP row_ror:N add — 16-lane full-sum reduction on the VALU pipe (not DS)
#define ROR_ADD(v, CTRL) \
    v += __int_as_float(__builtin_amdgcn_update_dpp(0, __float_as_int(v), CTRL, 0xf, 0xf, true))

// f32 -> bf16 (RNE) and packing helpers
__device__ __forceinline__ unsigned f2b(float f) {
    unsigned u = __float_as_uint(f);
    return (u + 0x7fffu + ((u >> 16) & 1u)) >> 16;
}
__device__ __forceinline__ unsigned pk(float a, float b) {   // a -> low16, b -> high16
    return f2b(a) | (f2b(b) << 16);
}
__device__ __forceinline__ float lo_f(unsigned w) { return __uint_as_float(w << 16); }
__device__ __forceinline__ float hi_f(unsigned w) { return __uint_as_float(w & 0xffff0000u); }

// -------- k_pool: window pooling: pooledT[b][c][w] --------
__global__ void k_pool(const float* __restrict__ x, float* __restrict__ pooled) {
    int bc = blockIdx.x;                 // b*96+c
    const float* xp = x + (size_t)bc * HH * HH;
    float* pp = pooled + (size_t)bc * NWIN;
    for (int w = threadIdx.x; w < NWIN; w += blockDim.x) {
        int wr = w >> 5, wc = w & 31;
        const float* base = xp + (wr * 7) * HH + wc * 7;
        float s = 0.f;
        #pragma unroll
        for (int i = 0; i < 7; ++i) {
            #pragma unroll
            for (int j = 0; j < 7; ++j) s += base[i * HH + j];
        }
        pp[w] = s * (1.0f / 49.0f);
    }
}

// -------- k_router: MLP logits (128 blocks x 64) + weff fold (striped) --------
__global__ __launch_bounds__(64) void k_router(
        const float* __restrict__ pooled,
        const float* __restrict__ w1, const float* __restrict__ b1,
        const float* __restrict__ w2, const float* __restrict__ b2,
        const float* __restrict__ xpw, const float* __restrict__ dtw,
        float* __restrict__ wcomb, float* __restrict__ logits) {
    __shared__ float sw1[PERK * CC];
    __shared__ float sb1[PERK];
    __shared__ float sw2[PERK];
    int b = blockIdx.x >> 4, slice = blockIdx.x & 15;
    int tid = threadIdx.x;
    // ---- weff slice: Wcomb[k][56][24] (used later by k_prodT only) ----
    for (int i = blockIdx.x * 64 + tid; i < 4 * 56 * PERK; i += 128 * 64) {
        int k = i / (56 * PERK), rem = i - k * (56 * PERK);
        int row = rem / PERK, c = rem - row * PERK;
        float v;
        if (row < PERK) {
            v = 0.f;
            #pragma unroll
            for (int r = 0; r < DTR; ++r)
                v += dtw[(k * PERK + row) * DTR + r] * xpw[(k * 38 + r) * PERK + c];
        } else {
            v = xpw[(k * 38 + (row - PERK + DTR)) * PERK + c];
        }
        wcomb[i] = v;
    }
    // ---- router ----
    for (int i = tid; i < PERK * CC; i += 64) sw1[i] = w1[i];
    if (tid < PERK) { sb1[tid] = b1[tid]; sw2[tid] = w2[tid]; }
    __syncthreads();
    int w = slice * 64 + tid;
    float hid[PERK];
    #pragma unroll
    for (int j = 0; j < PERK; ++j) hid[j] = sb1[j];
    const float* pp = pooled + (size_t)b * CC * NWIN + w;
    for (int c = 0; c < CC; ++c) {
        float pv = pp[(size_t)c * NWIN];
        #pragma unroll
        for (int j = 0; j < PERK; ++j) hid[j] += pv * sw1[j * CC + c];
    }
    float lg = b2[0];
    #pragma unroll
    for (int j = 0; j < PERK; ++j) {
        float hv = hid[j];
        float g = 0.5f * hv * (1.0f + erff(hv * 0.7071067811865476f));
        lg += g * sw2[j];
    }
    logits[b * NWIN + w] = lg;
}

// -------- k_rankF: fused softmax + stable descending rank (128 blocks x 64) --------
__global__ __launch_bounds__(64) void k_rankF(const float* __restrict__ logits,
        float* __restrict__ probs, float* __restrict__ rw,
        int* __restrict__ rank, int* __restrict__ sel) {
    __shared__ __attribute__((aligned(16))) float sp[NWIN];
    __shared__ float red[64];
    int b = blockIdx.x >> 4, slice = blockIdx.x & 15;
    int tid = threadIdx.x;
    for (int i = tid; i < NWIN / 4; i += 64)
        ((float4*)sp)[i] = ((const float4*)(logits + (size_t)b * NWIN))[i];
    __syncthreads();
    float m = -1e30f;
    for (int i = tid; i < NWIN; i += 64) m = fmaxf(m, sp[i]);
    red[tid] = m; __syncthreads();
    for (int o = 32; o > 0; o >>= 1) { if (tid < o) red[tid] = fmaxf(red[tid], red[tid + o]); __syncthreads(); }
    float mx = red[0]; __syncthreads();
    for (int i = tid; i < NWIN; i += 64) sp[i] = expf(sp[i] - mx);
    __syncthreads();
    float s = 0.f;
    for (int i = tid; i < NWIN; i += 64) s += sp[i];
    red[tid] = s; __syncthreads();
    for (int o = 32; o > 0; o >>= 1) { if (tid < o) red[tid] += red[tid + o]; __syncthreads(); }
    float sum = red[0]; __syncthreads();
    for (int i = tid; i < NWIN; i += 64) sp[i] = sp[i] / sum;
    __syncthreads();
    int w = slice * 64 + tid;
    float p = sp[w];
    probs[b * NWIN + w] = p;
    int r = 0;
    for (int j = 0; j < NWIN; j += 4) {
        float4 pj = *(const float4*)&sp[j];
        r += (int)((pj.x > p) || (pj.x == p && (j + 0) < w));
        r += (int)((pj.y > p) || (pj.y == p && (j + 1) < w));
        r += (int)((pj.z > p) || (pj.z == p && (j + 2) < w));
        r += (int)((pj.w > p) || (pj.w == p && (j + 3) < w));
    }
    rank[b * NWIN + w] = r;
    if (r < TOPK) { sel[b * TOPK + r] = w; rw[b * TOPK + r] = p; }
}

// softplus via hardware exp/log
__device__ __forceinline__ float softplus_f(float v) {
    return fmaxf(v, 0.f) + __logf(1.0f + __expf(-fabsf(v)));
}

// chunk t (= scan-window index) -> selected-window id
__device__ __forceinline__ int window_wsel(const int* sel, int b, int k, int t) {
    int qscan = (k >= 2) ? (255 - t) : t;
    int selidx = (k & 1) ? (((qscan & 15) << 4) | (qscan >> 4)) : qscan;
    return sel[b * TOPK + selidx];
}

// -------- k_gather: scattered x -> dense xs [blk][24][52], barrier-free streaming --------
__global__ __launch_bounds__(256) void k_gather(const float* __restrict__ x,
        const int* __restrict__ sel, float* __restrict__ xsd) {
    const int total = NBK * TCH * XROW;   // 10,223,616
    for (int e = blockIdx.x * 256 + threadIdx.x; e < total; e += gridDim.x * 256) {
        int blk = e / XROW;
        int rem = e - blk * XROW;
        int d2 = rem / LCP, j = rem - d2 * LCP;
        float v = 0.f;
        if (j < 49) {
            int t = blk & 255, bk = blk >> 8, k = bk & 3, b = bk >> 2;
            int wsel = window_wsel(sel, b, k, t);
            int pix = (k >= 2) ? 48 - j : j;
            int q7 = pix / 7, r7 = pix - q7 * 7;
            int wi = (k & 1) ? r7 : q7;
            int wj = (k & 1) ? q7 : r7;
            v = x[(((size_t)b * CC + 4 * d2 + k) * HH + (wsel >> 5) * 7 + wi) * HH
                  + (wsel & 31) * 7 + wj];
        }
        xsd[e] = v;
    }
}

// -------- k_prodT: proj (2-row-paired tasks) -> bf16 stage + f32 carries --------
__global__ __launch_bounds__(384, 4) void k_prodT(
        const float* __restrict__ xsd, const float* __restrict__ wcomb,
        const float* __restrict__ dtb, const float* __restrict__ alogs,
        float* __restrict__ stage, float* __restrict__ carrP, float* __restrict__ carrS) {
    __shared__ __attribute__((aligned(16))) float sxs[PERK][LCP];
    __shared__ __attribute__((aligned(16))) float sprj[56][LCP];  // 0..23 dl, 24..39 B, 40..55 C
    __shared__ float swt[56 * PERK];
    __shared__ float sbias[PERK];
    int blk = blockIdx.x; int k = (blk >> 8) & 3;
    int tid = threadIdx.x;
    const float4* xin = (const float4*)(xsd + (size_t)blk * XROW);
    for (int i = tid; i < XROW / 4; i += 384) ((float4*)sxs)[i] = xin[i];
    for (int i = tid; i < 56 * PERK; i += 384) swt[i] = wcomb[k * (56 * PERK) + i];
    if (tid < PERK) sbias[tid] = dtb[k * PERK + tid];
    if (tid < 168) { int r = tid / 3, j = 49 + tid % 3; sprj[r][j] = 0.f; }
    __syncthreads();
    // projection: 28 row-pairs x 13 groups = 364 tasks, exactly <=1 per thread
    if (tid < 28 * NG) {
        int rp = tid / NG, g = tid - rp * NG; int j = g * 4;
        int row0 = rp * 2, row1 = row0 + 1;
        bool isdl = (row0 < PERK);
        float bs0 = isdl ? sbias[row0] : 0.f;
        float bs1 = isdl ? sbias[row1] : 0.f;
        float a0x = bs0, a0y = bs0, a0z = bs0, a0w = bs0;
        float a1x = bs1, a1y = bs1, a1z = bs1, a1w = bs1;
        #pragma unroll
        for (int d2 = 0; d2 < PERK; ++d2) {
            float w0 = swt[row0 * PERK + d2];
            float w1 = swt[row1 * PERK + d2];
            float4 v = *(const float4*)&sxs[d2][j];
            a0x += w0 * v.x; a0y += w0 * v.y; a0z += w0 * v.z; a0w += w0 * v.w;
            a1x += w1 * v.x; a1y += w1 * v.y; a1z += w1 * v.z; a1w += w1 * v.w;
        }
        if (isdl) {
            a0x = softplus_f(a0x); a0y = softplus_f(a0y); a0z = softplus_f(a0z); a0w = softplus_f(a0w);
            a1x = softplus_f(a1x); a1y = softplus_f(a1y); a1z = softplus_f(a1z); a1w = softplus_f(a1w);
        }
        if (g < 12) {
            float4 o0 = {a0x, a0y, a0z, a0w}; *(float4*)&sprj[row0][j] = o0;
            float4 o1 = {a1x, a1y, a1z, a1w}; *(float4*)&sprj[row1][j] = o1;
        } else {
            sprj[row0][j] = a0x; sprj[row1][j] = a1x;
        }
    }
    __syncthreads();
    // bf16-packed transposed dump: P[13][24] uint4 = (dl,xs)x4 steps; Q[13][16] uint4 = (B,C)x4
    uint4* sgP = (uint4*)(stage + (size_t)blk * WST4);
    uint4* sgQ = sgP + 312;
    for (int tsk = tid; tsk < 312; tsk += 384) {
        int g4 = tsk / 24, d2 = tsk - g4 * 24; int j = g4 * 4;
        uint4 o;
        o.x = pk(sprj[d2][j + 0], sxs[d2][j + 0]);
        o.y = pk(sprj[d2][j + 1], sxs[d2][j + 1]);
        o.z = pk(sprj[d2][j + 2], sxs[d2][j + 2]);
        o.w = pk(sprj[d2][j + 3], sxs[d2][j + 3]);
        sgP[tsk] = o;
    }
    for (int tsk = tid; tsk < 208; tsk += 384) {
        int g4 = tsk / 16, s2 = tsk - g4 * 16; int j = g4 * 4;
        uint4 o;
        o.x = pk(sprj[24 + s2][j + 0], sprj[40 + s2][j + 0]);
        o.y = pk(sprj[24 + s2][j + 1], sprj[40 + s2][j + 1]);
        o.z = pk(sprj[24 + s2][j + 2], sprj[40 + s2][j + 2]);
        o.w = pk(sprj[24 + s2][j + 3], sprj[40 + s2][j + 3]);
        sgQ[tsk] = o;
    }
    // phase-1 carries in f32 (from LDS), exp2-folded with raw v_exp_f32
    int d = tid >> 4, s = tid & 15;
    float A2 = -__expf(alogs[(k * PERK + d) * DST + s]) * LOG2E;
    float P = 1.f, S = 0.f;
    for (int g = 0; g < NG; ++g) {
        int j = g * 4;
        float4 dl4 = *(const float4*)&sprj[d][j];        // pads = 0
        float4 xs4 = *(const float4*)&sxs[d][j];
        float4 B4  = *(const float4*)&sprj[24 + s][j];
        float aa;
        aa = EXP2F(dl4.x * A2); S = aa * S + (dl4.x * xs4.x) * B4.x; P *= aa;
        aa = EXP2F(dl4.y * A2); S = aa * S + (dl4.y * xs4.y) * B4.y; P *= aa;
        aa = EXP2F(dl4.z * A2); S = aa * S + (dl4.z * xs4.z) * B4.z; P *= aa;
        aa = EXP2F(dl4.w * A2); S = aa * S + (dl4.w * xs4.w) * B4.w; P *= aa;
    }
    size_t cidx = (size_t)blk * 384 + tid;
    carrP[cidx] = P; carrS[cidx] = S;
}

// -------- k_carry: scan across 256 windows (hin may alias carrP: read-before-write) --------
__global__ void k_carry(const float* carrP, const float* carrS, float* hin) {
    int gid = blockIdx.x * blockDim.x + threadIdx.x;   // 12288
    int bk = gid / 384, ds = gid - bk * 384;
    float Hv = 0.f;
    for (int t = 0; t < TCH; ++t) {
        size_t idx = ((size_t)bk * TCH + t) * 384 + ds;
        float pv = carrP[idx], sv = carrS[idx];
        hin[idx] = Hv;
        Hv = pv * Hv + sv;
    }
}

// one recurrence step from packed words: pw=(dl,xs), qw=(B,C); hv = h-chain register
#define BST(hv, widx, pw, qw, jj)                                                  \
    {                                                                              \
        float dl_ = lo_f(pw), xs_ = hi_f(pw), Bv_ = lo_f(qw), Cv_ = hi_f(qw);      \
        float aa_ = EXP2F(dl_ * A2);                                               \
        hv = aa_ * hv + (dl_ * xs_) * Bv_;                                         \
        float part_ = hv * Cv_;                                                    \
        ROR_ADD(part_, 0x121); ROR_ADD(part_, 0x122);                              \
        ROR_ADD(part_, 0x124); ROR_ADD(part_, 0x128);                              \
        if (s == 0 && (jj) < 49) sy[widx][d][jj] = part_ + xs_ * Dsr;              \
    }

// -------- k_scanT: TWO windows per block, interleaved chains; y -> xsd heads --------
__global__ __launch_bounds__(384, 4) void k_scanT(
        const float* __restrict__ alogs, const float* __restrict__ dsv,
        const float* __restrict__ hin, const float* __restrict__ stage,
        float* __restrict__ xsd) {
    __shared__ __attribute__((aligned(16))) float sy[2][PERK][LCP];
    int blk2 = blockIdx.x;                 // 0..4095
    int w0 = blk2 * 2, w1 = w0 + 1;        // same bk (w0 even, 256 windows per bk)
    int k = (w0 >> 8) & 3;
    int tid = threadIdx.x;
    int d = tid >> 4, s = tid & 15;
    float A2 = -__expf(alogs[(k * PERK + d) * DST + s]) * LOG2E;
    float Dsr = dsv[k * PERK + d];
    float h0 = hin[(size_t)w0 * 384 + tid];
    float h1 = hin[(size_t)w1 * 384 + tid];
    const uint4* pP0 = (const uint4*)(stage + (size_t)w0 * WST4) + d;
    const uint4* pQ0 = (const uint4*)(stage + (size_t)w0 * WST4) + 312 + s;
    const uint4* pP1 = (const uint4*)(stage + (size_t)w1 * WST4) + d;
    const uint4* pQ1 = (const uint4*)(stage + (size_t)w1 * WST4) + 312 + s;
    // depth-2 prefetch per window; two independent chains interleaved for ILP
    uint4 P0c = pP0[0],  Q0c = pQ0[0],  P1c = pP1[0],  Q1c = pQ1[0];
    uint4 P0n = pP0[24], Q0n = pQ0[16], P1n = pP1[24], Q1n = pQ1[16];
    for (int g4 = 0; g4 < NG; ++g4) {
        uint4 a0 = P0c, b0 = Q0c, a1 = P1c, b1 = Q1c;
        P0c = P0n; Q0c = Q0n; P1c = P1n; Q1c = Q1n;
        if (g4 + 2 < NG) {
            int jP = (g4 + 2) * 24, jQ = (g4 + 2) * 16;
            P0n = pP0[jP]; Q0n = pQ0[jQ]; P1n = pP1[jP]; Q1n = pQ1[jQ];
        }
        int j = g4 * 4;
        BST(h0, 0, a0.x, b0.x, j);     BST(h1, 1, a1.x, b1.x, j);
        BST(h0, 0, a0.y, b0.y, j + 1); BST(h1, 1, a1.y, b1.y, j + 1);
        BST(h0, 0, a0.z, b0.z, j + 2); BST(h1, 1, a1.z, b1.z, j + 2);
        BST(h0, 0, a0.w, b0.w, j + 3); BST(h1, 1, a1.w, b1.w, j + 3);
    }
    __syncthreads();
    float* y0 = xsd + (size_t)w0 * XROW;
    float* y1 = xsd + (size_t)w1 * XROW;
    for (int idx = tid; idx < PERK * 49; idx += 384) {
        int j = idx / PERK, d2 = idx - j * PERK;
        y0[idx] = sy[0][d2][j];
        y1[idx] = sy[1][d2][j];
    }
}

// -------- k_out: one block per (b,w); FULLY-CONTIGUOUS 18.8KB out write --------
// selected: out = x + p*y (ytile gather via qo = rank); unselected: out = x*(1+p)
__global__ __launch_bounds__(256) void k_out(const float* __restrict__ ysrc,
        const float* __restrict__ x, const int* __restrict__ rank,
        const float* __restrict__ probs, const float* __restrict__ rw,
        float* __restrict__ out) {
    __shared__ float ytile[CC * 49];
    int w = blockIdx.x & 1023; int b = blockIdx.x >> 10;
    int r = rank[b * NWIN + w];
    int tid = threadIdx.x;
    float* ob = out + ((size_t)(b * NWIN + w) * CC) * 49;
    int gi0 = (w >> 5) * 7, gj0 = (w & 31) * 7;
    if (r < TOPK) {
        int qo = r;
        float p = rw[b * TOPK + qo];
        for (int idx = tid; idx < CC * 49; idx += 256) {
            int k = idx / 1176; int r1 = idx - k * 1176;
            int u = r1 / 168;   int r2 = r1 - u * 168;
            int wj = r2 / 24;   int d = r2 - wj * 24;
            int rest = qo * 7 + u;
            int b2 = rest & 15; int aw = rest >> 4;
            int wi = aw % 7;    int a = aw / 7;
            int q   = (k & 1) ? (b2 * 16 + a) : (a * 16 + b2);
            int pix = (k & 1) ? (wj * 7 + wi) : (wi * 7 + wj);
            int uu = q * 49 + pix;
            int l = (k >= 2) ? (LL - 1 - uu) : uu;
            int bk = b * 4 + k;
            int t2 = l / 49, jj = l - t2 * 49;
            ytile[(k * PERK + d) * 49 + u * 7 + wj] =
                p * ysrc[((size_t)(bk * 256 + t2)) * XROW + jj * PERK + d];
        }
        __syncthreads();
        for (int e = tid; e < CC * 49; e += 256) {
            int C = e / 49, cell = e - C * 49;
            int u = cell / 7, wj = cell - u * 7;
            float xv = x[(((size_t)b * CC + C) * HH + gi0 + u) * HH + gj0 + wj];
            ob[e] = xv + ytile[e];
        }
    } else {
        float f = 1.0f + probs[b * NWIN + w];
        for (int e = tid; e < CC * 49; e += 256) {
            int C = e / 49, cell = e - C * 49;
            int u = cell / 7, wj = cell - u * 7;
            float xv = x[(((size_t)b * CC + C) * HH + gi0 + u) * HH + gj0 + wj];
            ob[e] = xv * f;
        }
    }
}

extern "C" void kernel_launch(void* const* d_in, const int* in_sizes, int n_in,
                              void* d_out, int out_size, void* d_ws, size_t ws_size,
                              hipStream_t stream) {
    const float* x   = (const float*)d_in[0];
    const float* w1  = (const float*)d_in[1];
    const float* b1  = (const float*)d_in[2];
    const float* w2  = (const float*)d_in[3];
    const float* b2  = (const float*)d_in[4];
    const float* xpw = (const float*)d_in[5];
    const float* dtw = (const float*)d_in[6];
    const float* dtb = (const float*)d_in[7];
    const float* alg = (const float*)d_in[8];
    const float* dsv = (const float*)d_in[9];
    float* out = (float*)d_out;
    float* ws  = (float*)d_ws;

    float* pooled = ws + OFF_POOL;
    float* logits = ws + OFF_LOG;
    float* probs  = ws + OFF_PROB;
    float* rwv    = ws + OFF_RW;
    int*   rank   = (int*)(ws + OFF_RANK);
    int*   sel    = (int*)(ws + OFF_SEL);
    float* wcomb  = ws + OFF_WEFF;
    float* cP  = ws + OFF_CP;       // also hin after carry
    float* cS  = ws + OFF_CS;
    float* xsd = ws + OFF_XSD;      // xs dense; y written into head by k_scanT
    float* stage = ws + OFF_STG;

    k_pool  <<<BBATCH * CC, 256, 0, stream>>>(x, pooled);
    k_router<<<BBATCH * 16, 64, 0, stream>>>(pooled, w1, b1, w2, b2, xpw, dtw, wcomb, logits);
    k_rankF <<<BBATCH * 16, 64, 0, stream>>>(logits, probs, rwv, rank, sel);
    k_gather<<<2048, 256, 0, stream>>>(x, sel, xsd);
    k_prodT <<<NBK * TCH, 384, 0, stream>>>(xsd, wcomb, dtb, alg, stage, cP, cS);
    k_carry <<<48, 256, 0, stream>>>(cP, cS, cP);     // hin aliases cP (read-before-write)
    k_scanT <<<NBK * TCH / 2, 384, 0, stream>>>(alg, dsv, cP, stage, xsd);
    k_out   <<<BBATCH * NWIN, 256, 0, stream>>>(xsd, x, rank, probs, rwv, out);
}

// Round 19
// 449.591 us; speedup vs baseline: 1.0953x; 1.0953x over previous
//
#include <hip/hip_runtime.h>
#include <math.h>

// Problem constants
#define BBATCH 8
#define CC 96
#define HH 224
#define NHW 32            // 224/7 windows per side
#define NWIN 1024
#define TOPK 256
#define PERK 24
#define DST 16
#define DTR 6
#define LL 12544          // 256*49
#define LCP 52            // padded row length (49 used + 3 zero pad)
#define NG 13             // float4 groups per row
#define TCH 256           // one chunk = ONE scan window (49 steps)
#define NBK 32            // B*4 directions
#define XROW 1248         // xs floats per window: 24 x 52 (y reuses head: 1176)
#define WST4 2080         // bf16 stage floats per window: P 312 uint4 + Q 208 uint4
#define LOG2E 1.4426950408889634f

// fast hardware exp2: exactly one v_exp_f32
#define EXP2F(x) __builtin_amdgcn_exp2f(x)

// workspace offsets (floats) — total 34,374,912 floats = 137.5 MB (< proven 164.8)
#define OFF_POOL 0
#define OFF_LOG  786432
#define OFF_PROB 794624
#define OFF_RW   802816
#define OFF_RANK 804864
#define OFF_SEL  813056
#define OFF_WEFF 815104
#define OFF_CP   820480      // 3,145,728; reused as hin (read-before-write in carry)
#define OFF_CS   3966208     // 3,145,728
#define OFF_XSD  7111936     // 10,223,616: xs dense [8192][24][52]; y written into head
#define OFF_STG  17335552    // 8192*2080 = 17,039,360: bf16-packed stage

// DPP row_ror:N add — 16-lane full-sum reduction on the VALU pipe (not DS)
#define ROR_ADD(v, CTRL) \
    v += __int_as_float(__builtin_amdgcn_update_dpp(0, __float_as_int(v), CTRL, 0xf, 0xf, true))

// f32 -> bf16 (RNE) and packing helpers
__device__ __forceinline__ unsigned f2b(float f) {
    unsigned u = __float_as_uint(f);
    return (u + 0x7fffu + ((u >> 16) & 1u)) >> 16;
}
__device__ __forceinline__ unsigned pk(float a, float b) {   // a -> low16, b -> high16
    return f2b(a) | (f2b(b) << 16);
}
__device__ __forceinline__ float lo_f(unsigned w) { return __uint_as_float(w << 16); }
__device__ __forceinline__ float hi_f(unsigned w) { return __uint_as_float(w & 0xffff0000u); }

// -------- k_pool: window pooling: pooledT[b][c][w] --------
__global__ void k_pool(const float* __restrict__ x, float* __restrict__ pooled) {
    int bc = blockIdx.x;                 // b*96+c
    const float* xp = x + (size_t)bc * HH * HH;
    float* pp = pooled + (size_t)bc * NWIN;
    for (int w = threadIdx.x; w < NWIN; w += blockDim.x) {
        int wr = w >> 5, wc = w & 31;
        const float* base = xp + (wr * 7) * HH + wc * 7;
        float s = 0.f;
        #pragma unroll
        for (int i = 0; i < 7; ++i) {
            #pragma unroll
            for (int j = 0; j < 7; ++j) s += base[i * HH + j];
        }
        pp[w] = s * (1.0f / 49.0f);
    }
}

// -------- k_router: MLP logits (128 blocks x 64) + weff fold (striped) --------
__global__ __launch_bounds__(64) void k_router(
        const float* __restrict__ pooled,
        const float* __restrict__ w1, const float* __restrict__ b1,
        const float* __restrict__ w2, const float* __restrict__ b2,
        const float* __restrict__ xpw, const float* __restrict__ dtw,
        float* __restrict__ wcomb, float* __restrict__ logits) {
    __shared__ float sw1[PERK * CC];
    __shared__ float sb1[PERK];
    __shared__ float sw2[PERK];
    int b = blockIdx.x >> 4, slice = blockIdx.x & 15;
    int tid = threadIdx.x;
    // ---- weff slice: Wcomb[k][56][24] (used later by k_prodT only) ----
    for (int i = blockIdx.x * 64 + tid; i < 4 * 56 * PERK; i += 128 * 64) {
        int k = i / (56 * PERK), rem = i - k * (56 * PERK);
        int row = rem / PERK, c = rem - row * PERK;
        float v;
        if (row < PERK) {
            v = 0.f;
            #pragma unroll
            for (int r = 0; r < DTR; ++r)
                v += dtw[(k * PERK + row) * DTR + r] * xpw[(k * 38 + r) * PERK + c];
        } else {
            v = xpw[(k * 38 + (row - PERK + DTR)) * PERK + c];
        }
        wcomb[i] = v;
    }
    // ---- router ----
    for (int i = tid; i < PERK * CC; i += 64) sw1[i] = w1[i];
    if (tid < PERK) { sb1[tid] = b1[tid]; sw2[tid] = w2[tid]; }
    __syncthreads();
    int w = slice * 64 + tid;
    float hid[PERK];
    #pragma unroll
    for (int j = 0; j < PERK; ++j) hid[j] = sb1[j];
    const float* pp = pooled + (size_t)b * CC * NWIN + w;
    for (int c = 0; c < CC; ++c) {
        float pv = pp[(size_t)c * NWIN];
        #pragma unroll
        for (int j = 0; j < PERK; ++j) hid[j] += pv * sw1[j * CC + c];
    }
    float lg = b2[0];
    #pragma unroll
    for (int j = 0; j < PERK; ++j) {
        float hv = hid[j];
        float g = 0.5f * hv * (1.0f + erff(hv * 0.7071067811865476f));
        lg += g * sw2[j];
    }
    logits[b * NWIN + w] = lg;
}

// -------- k_rankF: fused softmax + stable descending rank (128 blocks x 64) --------
__global__ __launch_bounds__(64) void k_rankF(const float* __restrict__ logits,
        float* __restrict__ probs, float* __restrict__ rw,
        int* __restrict__ rank, int* __restrict__ sel) {
    __shared__ __attribute__((aligned(16))) float sp[NWIN];
    __shared__ float red[64];
    int b = blockIdx.x >> 4, slice = blockIdx.x & 15;
    int tid = threadIdx.x;
    for (int i = tid; i < NWIN / 4; i += 64)
        ((float4*)sp)[i] = ((const float4*)(logits + (size_t)b * NWIN))[i];
    __syncthreads();
    float m = -1e30f;
    for (int i = tid; i < NWIN; i += 64) m = fmaxf(m, sp[i]);
    red[tid] = m; __syncthreads();
    for (int o = 32; o > 0; o >>= 1) { if (tid < o) red[tid] = fmaxf(red[tid], red[tid + o]); __syncthreads(); }
    float mx = red[0]; __syncthreads();
    for (int i = tid; i < NWIN; i += 64) sp[i] = expf(sp[i] - mx);
    __syncthreads();
    float s = 0.f;
    for (int i = tid; i < NWIN; i += 64) s += sp[i];
    red[tid] = s; __syncthreads();
    for (int o = 32; o > 0; o >>= 1) { if (tid < o) red[tid] += red[tid + o]; __syncthreads(); }
    float sum = red[0]; __syncthreads();
    for (int i = tid; i < NWIN; i += 64) sp[i] = sp[i] / sum;
    __syncthreads();
    int w = slice * 64 + tid;
    float p = sp[w];
    probs[b * NWIN + w] = p;
    int r = 0;
    for (int j = 0; j < NWIN; j += 4) {
        float4 pj = *(const float4*)&sp[j];
        r += (int)((pj.x > p) || (pj.x == p && (j + 0) < w));
        r += (int)((pj.y > p) || (pj.y == p && (j + 1) < w));
        r += (int)((pj.z > p) || (pj.z == p && (j + 2) < w));
        r += (int)((pj.w > p) || (pj.w == p && (j + 3) < w));
    }
    rank[b * NWIN + w] = r;
    if (r < TOPK) { sel[b * TOPK + r] = w; rw[b * TOPK + r] = p; }
}

// softplus via hardware exp/log
__device__ __forceinline__ float softplus_f(float v) {
    return fmaxf(v, 0.f) + __logf(1.0f + __expf(-fabsf(v)));
}

// chunk t (= scan-window index) -> selected-window id
__device__ __forceinline__ int window_wsel(const int* sel, int b, int k, int t) {
    int qscan = (k >= 2) ? (255 - t) : t;
    int selidx = (k & 1) ? (((qscan & 15) << 4) | (qscan >> 4)) : qscan;
    return sel[b * TOPK + selidx];
}

// -------- k_gather: scattered x -> dense xs [blk][24][52], barrier-free streaming --------
__global__ __launch_bounds__(256) void k_gather(const float* __restrict__ x,
        const int* __restrict__ sel, float* __restrict__ xsd) {
    const int total = NBK * TCH * XROW;   // 10,223,616
    for (int e = blockIdx.x * 256 + threadIdx.x; e < total; e += gridDim.x * 256) {
        int blk = e / XROW;
        int rem = e - blk * XROW;
        int d2 = rem / LCP, j = rem - d2 * LCP;
        float v = 0.f;
        if (j < 49) {
            int t = blk & 255, bk = blk >> 8, k = bk & 3, b = bk >> 2;
            int wsel = window_wsel(sel, b, k, t);
            int pix = (k >= 2) ? 48 - j : j;
            int q7 = pix / 7, r7 = pix - q7 * 7;
            int wi = (k & 1) ? r7 : q7;
            int wj = (k & 1) ? q7 : r7;
            v = x[(((size_t)b * CC + 4 * d2 + k) * HH + (wsel >> 5) * 7 + wi) * HH
                  + (wsel & 31) * 7 + wj];
        }
        xsd[e] = v;
    }
}

// -------- k_prodT: proj (2-row-paired tasks) -> bf16 stage + f32 carries --------
__global__ __launch_bounds__(384, 4) void k_prodT(
        const float* __restrict__ xsd, const float* __restrict__ wcomb,
        const float* __restrict__ dtb, const float* __restrict__ alogs,
        float* __restrict__ stage, float* __restrict__ carrP, float* __restrict__ carrS) {
    __shared__ __attribute__((aligned(16))) float sxs[PERK][LCP];
    __shared__ __attribute__((aligned(16))) float sprj[56][LCP];  // 0..23 dl, 24..39 B, 40..55 C
    __shared__ float swt[56 * PERK];
    __shared__ float sbias[PERK];
    int blk = blockIdx.x; int k = (blk >> 8) & 3;
    int tid = threadIdx.x;
    const float4* xin = (const float4*)(xsd + (size_t)blk * XROW);
    for (int i = tid; i < XROW / 4; i += 384) ((float4*)sxs)[i] = xin[i];
    for (int i = tid; i < 56 * PERK; i += 384) swt[i] = wcomb[k * (56 * PERK) + i];
    if (tid < PERK) sbias[tid] = dtb[k * PERK + tid];
    if (tid < 168) { int r = tid / 3, j = 49 + tid % 3; sprj[r][j] = 0.f; }
    __syncthreads();
    // projection: 28 row-pairs x 13 groups = 364 tasks, exactly <=1 per thread
    if (tid < 28 * NG) {
        int rp = tid / NG, g = tid - rp * NG; int j = g * 4;
        int row0 = rp * 2, row1 = row0 + 1;
        bool isdl = (row0 < PERK);
        float bs0 = isdl ? sbias[row0] : 0.f;
        float bs1 = isdl ? sbias[row1] : 0.f;
        float a0x = bs0, a0y = bs0, a0z = bs0, a0w = bs0;
        float a1x = bs1, a1y = bs1, a1z = bs1, a1w = bs1;
        #pragma unroll
        for (int d2 = 0; d2 < PERK; ++d2) {
            float w0 = swt[row0 * PERK + d2];
            float w1 = swt[row1 * PERK + d2];
            float4 v = *(const float4*)&sxs[d2][j];
            a0x += w0 * v.x; a0y += w0 * v.y; a0z += w0 * v.z; a0w += w0 * v.w;
            a1x += w1 * v.x; a1y += w1 * v.y; a1z += w1 * v.z; a1w += w1 * v.w;
        }
        if (isdl) {
            a0x = softplus_f(a0x); a0y = softplus_f(a0y); a0z = softplus_f(a0z); a0w = softplus_f(a0w);
            a1x = softplus_f(a1x); a1y = softplus_f(a1y); a1z = softplus_f(a1z); a1w = softplus_f(a1w);
        }
        if (g < 12) {
            float4 o0 = {a0x, a0y, a0z, a0w}; *(float4*)&sprj[row0][j] = o0;
            float4 o1 = {a1x, a1y, a1z, a1w}; *(float4*)&sprj[row1][j] = o1;
        } else {
            sprj[row0][j] = a0x; sprj[row1][j] = a1x;
        }
    }
    __syncthreads();
    // bf16-packed transposed dump: P[13][24] uint4 = (dl,xs)x4 steps; Q[13][16] uint4 = (B,C)x4
    uint4* sgP = (uint4*)(stage + (size_t)blk * WST4);
    uint4* sgQ = sgP + 312;
    for (int tsk = tid; tsk < 312; tsk += 384) {
        int g4 = tsk / 24, d2 = tsk - g4 * 24; int j = g4 * 4;
        uint4 o;
        o.x = pk(sprj[d2][j + 0], sxs[d2][j + 0]);
        o.y = pk(sprj[d2][j + 1], sxs[d2][j + 1]);
        o.z = pk(sprj[d2][j + 2], sxs[d2][j + 2]);
        o.w = pk(sprj[d2][j + 3], sxs[d2][j + 3]);
        sgP[tsk] = o;
    }
    for (int tsk = tid; tsk < 208; tsk += 384) {
        int g4 = tsk / 16, s2 = tsk - g4 * 16; int j = g4 * 4;
        uint4 o;
        o.x = pk(sprj[24 + s2][j + 0], sprj[40 + s2][j + 0]);
        o.y = pk(sprj[24 + s2][j + 1], sprj[40 + s2][j + 1]);
        o.z = pk(sprj[24 + s2][j + 2], sprj[40 + s2][j + 2]);
        o.w = pk(sprj[24 + s2][j + 3], sprj[40 + s2][j + 3]);
        sgQ[tsk] = o;
    }
    // phase-1 carries in f32 (from LDS), exp2-folded with raw v_exp_f32
    int d = tid >> 4, s = tid & 15;
    float A2 = -__expf(alogs[(k * PERK + d) * DST + s]) * LOG2E;
    float P = 1.f, S = 0.f;
    for (int g = 0; g < NG; ++g) {
        int j = g * 4;
        float4 dl4 = *(const float4*)&sprj[d][j];        // pads = 0
        float4 xs4 = *(const float4*)&sxs[d][j];
        float4 B4  = *(const float4*)&sprj[24 + s][j];
        float aa;
        aa = EXP2F(dl4.x * A2); S = aa * S + (dl4.x * xs4.x) * B4.x; P *= aa;
        aa = EXP2F(dl4.y * A2); S = aa * S + (dl4.y * xs4.y) * B4.y; P *= aa;
        aa = EXP2F(dl4.z * A2); S = aa * S + (dl4.z * xs4.z) * B4.z; P *= aa;
        aa = EXP2F(dl4.w * A2); S = aa * S + (dl4.w * xs4.w) * B4.w; P *= aa;
    }
    size_t cidx = (size_t)blk * 384 + tid;
    carrP[cidx] = P; carrS[cidx] = S;
}

// -------- k_cb: blocks [0,48) carry; blocks [48,..) base via LDS transpose --------
// base block = (b, wr, cg of 8 channels): coalesced stripe reads, 1568B-contiguous writes
#define CSTR 1575      // channel stride in buf (7 rows x 225)
#define RSTR 225       // padded row stride (225 % 32 = 1: no ri bank aliasing)
__global__ __launch_bounds__(256) void k_cb(const float* carrP, const float* carrS,
        float* hin, const float* __restrict__ x, const float* __restrict__ probs,
        const int* __restrict__ rank, float* __restrict__ out) {
    __shared__ float buf[8 * CSTR];    // 50.4 KB
    __shared__ float fmul[NHW];
    __shared__ int   fsel[NHW];
    if (blockIdx.x < 48) {
        int gid = blockIdx.x * 256 + threadIdx.x;   // 12288
        int bk = gid / 384, ds = gid - bk * 384;
        float Hv = 0.f;
        for (int t = 0; t < TCH; ++t) {
            size_t idx = ((size_t)bk * TCH + t) * 384 + ds;
            float pv = carrP[idx], sv = carrS[idx];
            hin[idx] = Hv;
            Hv = pv * Hv + sv;
        }
        return;
    }
    int bid = blockIdx.x - 48;          // 0..3071
    int cg = bid % 12; int rem = bid / 12;
    int wr = rem % NHW; int b = rem / NHW;
    int tid = threadIdx.x;
    // coalesced stripe load: 8 channels x 7 rows x 224 cols
    for (int i = tid; i < 8 * 7 * 224; i += 256) {
        int ch = i / 1568; int r2 = i - ch * 1568;
        int r = r2 / 224, col = r2 - r * 224;
        buf[ch * CSTR + r * RSTR + col] =
            x[(((size_t)b * CC + cg * 8 + ch) * HH + wr * 7 + r) * HH + col];
    }
    if (tid < NHW) {
        int w = wr * NHW + tid;
        fsel[tid] = (rank[b * NWIN + w] < TOPK);
        fmul[tid] = 1.0f + probs[b * NWIN + w];
    }
    __syncthreads();
    // contiguous writes: per window 8ch x 49 = 392 floats (1568 B)
    for (int idx = tid; idx < NHW * 8 * 49; idx += 256) {
        int wc = idx / 392; int r3 = idx - wc * 392;
        if (fsel[wc]) continue;
        int ch = r3 / 49; int rr = r3 - ch * 49;
        int ri = rr / 7, rj = rr - ri * 7;
        float v = buf[ch * CSTR + ri * RSTR + wc * 7 + rj];
        out[(((size_t)b * NWIN + wr * NHW + wc) * CC + cg * 8 + ch) * 49 + rr] = v * fmul[wc];
    }
}

// one recurrence step from packed words: pw=(dl,xs), qw=(B,C); hv = h-chain register
#define BST(hv, widx, pw, qw, jj)                                                  \
    {                                                                              \
        float dl_ = lo_f(pw), xs_ = hi_f(pw), Bv_ = lo_f(qw), Cv_ = hi_f(qw);      \
        float aa_ = EXP2F(dl_ * A2);                                               \
        hv = aa_ * hv + (dl_ * xs_) * Bv_;                                         \
        float part_ = hv * Cv_;                                                    \
        ROR_ADD(part_, 0x121); ROR_ADD(part_, 0x122);                              \
        ROR_ADD(part_, 0x124); ROR_ADD(part_, 0x128);                              \
        if (s == 0 && (jj) < 49) sy[widx][d][jj] = part_ + xs_ * Dsr;              \
    }

// -------- k_scanT: TWO windows per block, interleaved chains; y -> xsd heads --------
__global__ __launch_bounds__(384, 4) void k_scanT(
        const float* __restrict__ alogs, const float* __restrict__ dsv,
        const float* __restrict__ hin, const float* __restrict__ stage,
        float* __restrict__ xsd) {
    __shared__ __attribute__((aligned(16))) float sy[2][PERK][LCP];
    int blk2 = blockIdx.x;                 // 0..4095
    int w0 = blk2 * 2, w1 = w0 + 1;        // same bk (w0 even, 256 windows per bk)
    int k = (w0 >> 8) & 3;
    int tid = threadIdx.x;
    int d = tid >> 4, s = tid & 15;
    float A2 = -__expf(alogs[(k * PERK + d) * DST + s]) * LOG2E;
    float Dsr = dsv[k * PERK + d];
    float h0 = hin[(size_t)w0 * 384 + tid];
    float h1 = hin[(size_t)w1 * 384 + tid];
    const uint4* pP0 = (const uint4*)(stage + (size_t)w0 * WST4) + d;
    const uint4* pQ0 = (const uint4*)(stage + (size_t)w0 * WST4) + 312 + s;
    const uint4* pP1 = (const uint4*)(stage + (size_t)w1 * WST4) + d;
    const uint4* pQ1 = (const uint4*)(stage + (size_t)w1 * WST4) + 312 + s;
    // depth-2 prefetch per window; two independent chains interleaved for ILP
    uint4 P0c = pP0[0],  Q0c = pQ0[0],  P1c = pP1[0],  Q1c = pQ1[0];
    uint4 P0n = pP0[24], Q0n = pQ0[16], P1n = pP1[24], Q1n = pQ1[16];
    for (int g4 = 0; g4 < NG; ++g4) {
        uint4 a0 = P0c, b0 = Q0c, a1 = P1c, b1 = Q1c;
        P0c = P0n; Q0c = Q0n; P1c = P1n; Q1c = Q1n;
        if (g4 + 2 < NG) {
            int jP = (g4 + 2) * 24, jQ = (g4 + 2) * 16;
            P0n = pP0[jP]; Q0n = pQ0[jQ]; P1n = pP1[jP]; Q1n = pQ1[jQ];
        }
        int j = g4 * 4;
        BST(h0, 0, a0.x, b0.x, j);     BST(h1, 1, a1.x, b1.x, j);
        BST(h0, 0, a0.y, b0.y, j + 1); BST(h1, 1, a1.y, b1.y, j + 1);
        BST(h0, 0, a0.z, b0.z, j + 2); BST(h1, 1, a1.z, b1.z, j + 2);
        BST(h0, 0, a0.w, b0.w, j + 3); BST(h1, 1, a1.w, b1.w, j + 3);
    }
    __syncthreads();
    float* y0 = xsd + (size_t)w0 * XROW;
    float* y1 = xsd + (size_t)w1 * XROW;
    for (int idx = tid; idx < PERK * 49; idx += 384) {
        int j = idx / PERK, d2 = idx - j * PERK;
        y0[idx] = sy[0][d2][j];
        y1[idx] = sy[1][d2][j];
    }
}

// -------- k_yadd: selected windows written DIRECTLY: out = x + p*y (no RMW) --------
__global__ __launch_bounds__(256) void k_yadd(const float* __restrict__ ysrc,
        const float* __restrict__ x, const int* __restrict__ sel,
        const float* __restrict__ rw, float* __restrict__ out) {
    __shared__ float ytile[CC * 49];
    int qo = blockIdx.x & 255; int b = blockIdx.x >> 8;
    int wsel = sel[b * TOPK + qo];
    float p = rw[b * TOPK + qo];
    for (int idx = threadIdx.x; idx < CC * 49; idx += 256) {
        int k = idx / 1176; int r1 = idx - k * 1176;
        int u = r1 / 168;   int r2 = r1 - u * 168;
        int wj = r2 / 24;   int d = r2 - wj * 24;
        int rest = qo * 7 + u;
        int b2 = rest & 15; int aw = rest >> 4;
        int wi = aw % 7;    int a = aw / 7;
        int q   = (k & 1) ? (b2 * 16 + a) : (a * 16 + b2);
        int pix = (k & 1) ? (wj * 7 + wi) : (wi * 7 + wj);
        int uu = q * 49 + pix;
        int l = (k >= 2) ? (LL - 1 - uu) : uu;
        int bk = b * 4 + k;
        int t2 = l / 49, jj = l - t2 * 49;
        ytile[(k * PERK + d) * 49 + u * 7 + wj] =
            p * ysrc[((size_t)(bk * 256 + t2)) * XROW + jj * PERK + d];
    }
    __syncthreads();
    float* ob = out + ((size_t)(b * NWIN + wsel) * CC) * 49;
    int gi0 = (wsel >> 5) * 7, gj0 = (wsel & 31) * 7;
    for (int e = threadIdx.x; e < CC * 49; e += 256) {
        int C = e / 49, cell = e - C * 49;
        int u = cell / 7, wj = cell - u * 7;
        float xv = x[(((size_t)b * CC + C) * HH + gi0 + u) * HH + gj0 + wj];
        ob[e] = xv + ytile[e];
    }
}

extern "C" void kernel_launch(void* const* d_in, const int* in_sizes, int n_in,
                              void* d_out, int out_size, void* d_ws, size_t ws_size,
                              hipStream_t stream) {
    const float* x   = (const float*)d_in[0];
    const float* w1  = (const float*)d_in[1];
    const float* b1  = (const float*)d_in[2];
    const float* w2  = (const float*)d_in[3];
    const float* b2  = (const float*)d_in[4];
    const float* xpw = (const float*)d_in[5];
    const float* dtw = (const float*)d_in[6];
    const float* dtb = (const float*)d_in[7];
    const float* alg = (const float*)d_in[8];
    const float* dsv = (const float*)d_in[9];
    float* out = (float*)d_out;
    float* ws  = (float*)d_ws;

    float* pooled = ws + OFF_POOL;
    float* logits = ws + OFF_LOG;
    float* probs  = ws + OFF_PROB;
    float* rwv    = ws + OFF_RW;
    int*   rank   = (int*)(ws + OFF_RANK);
    int*   sel    = (int*)(ws + OFF_SEL);
    float* wcomb  = ws + OFF_WEFF;
    float* cP  = ws + OFF_CP;       // also hin after carry
    float* cS  = ws + OFF_CS;
    float* xsd = ws + OFF_XSD;      // xs dense; y written into head by k_scanT
    float* stage = ws + OFF_STG;

    k_pool  <<<BBATCH * CC, 256, 0, stream>>>(x, pooled);
    k_router<<<BBATCH * 16, 64, 0, stream>>>(pooled, w1, b1, w2, b2, xpw, dtw, wcomb, logits);
    k_rankF <<<BBATCH * 16, 64, 0, stream>>>(logits, probs, rwv, rank, sel);
    k_gather<<<2048, 256, 0, stream>>>(x, sel, xsd);
    k_prodT <<<NBK * TCH, 384, 0, stream>>>(xsd, wcomb, dtb, alg, stage, cP, cS);
    k_cb    <<<48 + BBATCH * NHW * 12, 256, 0, stream>>>(cP, cS, cP, x, probs, rank, out);
    k_scanT <<<NBK * TCH / 2, 384, 0, stream>>>(alg, dsv, cP, stage, xsd);
    k_yadd  <<<BBATCH * TOPK, 256, 0, stream>>>(xsd, x, sel, rwv, out);
}

// Round 20
// 426.801 us; speedup vs baseline: 1.1538x; 1.0534x over previous
//
#include <hip/hip_runtime.h>
#include <math.h>

// Problem constants
#define BBATCH 8
#define CC 96
#define HH 224
#define NHW 32            // 224/7 windows per side
#define NWIN 1024
#define TOPK 256
#define PERK 24
#define DST 16
#define DTR 6
#define LL 12544          // 256*49
#define LCP 52            // padded row length (49 used + 3 zero pad)
#define NG 13             // float4 groups per row
#define TCH 256           // one chunk = ONE scan window (49 steps)
#define NBK 32            // B*4 directions
#define XROW 1248         // xs floats per window: 24 x 52 (y reuses head: 1176)
#define WST4 2080         // bf16 stage floats per window: P 312 uint4 + Q 208 uint4
#define LOG2E 1.4426950408889634f

// fast hardware exp2: exactly one v_exp_f32
#define EXP2F(x) __builtin_amdgcn_exp2f(x)

// workspace offsets (floats) — total 34,374,912 floats = 137.5 MB (< proven 164.8)
#define OFF_POOL 0
#define OFF_LOG  786432
#define OFF_PROB 794624
#define OFF_RW   802816
#define OFF_RANK 804864
#define OFF_SEL  813056
#define OFF_WEFF 815104
#define OFF_CP   820480      // 3,145,728; reused as hin (read-before-write in carry)
#define OFF_CS   3966208     // 3,145,728
#define OFF_XSD  7111936     // 10,223,616: xs dense [8192][24][52]; y written into head
#define OFF_STG  17335552    // 8192*2080 = 17,039,360: bf16-packed stage

// DPP row_ror:N add — 16-lane full-sum reduction on the VALU pipe (not DS)
#define ROR_ADD(v, CTRL) \
    v += __int_as_float(__builtin_amdgcn_update_dpp(0, __float_as_int(v), CTRL, 0xf, 0xf, true))

// f32 -> bf16 (RNE) and packing helpers
__device__ __forceinline__ unsigned f2b(float f) {
    unsigned u = __float_as_uint(f);
    return (u + 0x7fffu + ((u >> 16) & 1u)) >> 16;
}
__device__ __forceinline__ unsigned pk(float a, float b) {   // a -> low16, b -> high16
    return f2b(a) | (f2b(b) << 16);
}
__device__ __forceinline__ float lo_f(unsigned w) { return __uint_as_float(w << 16); }
__device__ __forceinline__ float hi_f(unsigned w) { return __uint_as_float(w & 0xffff0000u); }

// -------- k_pool: window pooling: pooledT[b][c][w] --------
__global__ void k_pool(const float* __restrict__ x, float* __restrict__ pooled) {
    int bc = blockIdx.x;                 // b*96+c
    const float* xp = x + (size_t)bc * HH * HH;
    float* pp = pooled + (size_t)bc * NWIN;
    for (int w = threadIdx.x; w < NWIN; w += blockDim.x) {
        int wr = w >> 5, wc = w & 31;
        const float* base = xp + (wr * 7) * HH + wc * 7;
        float s = 0.f;
        #pragma unroll
        for (int i = 0; i < 7; ++i) {
            #pragma unroll
            for (int j = 0; j < 7; ++j) s += base[i * HH + j];
        }
        pp[w] = s * (1.0f / 49.0f);
    }
}

// -------- k_router: MLP logits (128 blocks x 64) + weff fold (striped) --------
__global__ __launch_bounds__(64) void k_router(
        const float* __restrict__ pooled,
        const float* __restrict__ w1, const float* __restrict__ b1,
        const float* __restrict__ w2, const float* __restrict__ b2,
        const float* __restrict__ xpw, const float* __restrict__ dtw,
        float* __restrict__ wcomb, float* __restrict__ logits) {
    __shared__ float sw1[PERK * CC];
    __shared__ float sb1[PERK];
    __shared__ float sw2[PERK];
    int b = blockIdx.x >> 4, slice = blockIdx.x & 15;
    int tid = threadIdx.x;
    // ---- weff slice: Wcomb[k][56][24] (used later by k_prodT only) ----
    for (int i = blockIdx.x * 64 + tid; i < 4 * 56 * PERK; i += 128 * 64) {
        int k = i / (56 * PERK), rem = i - k * (56 * PERK);
        int row = rem / PERK, c = rem - row * PERK;
        float v;
        if (row < PERK) {
            v = 0.f;
            #pragma unroll
            for (int r = 0; r < DTR; ++r)
                v += dtw[(k * PERK + row) * DTR + r] * xpw[(k * 38 + r) * PERK + c];
        } else {
            v = xpw[(k * 38 + (row - PERK + DTR)) * PERK + c];
        }
        wcomb[i] = v;
    }
    // ---- router ----
    for (int i = tid; i < PERK * CC; i += 64) sw1[i] = w1[i];
    if (tid < PERK) { sb1[tid] = b1[tid]; sw2[tid] = w2[tid]; }
    __syncthreads();
    int w = slice * 64 + tid;
    float hid[PERK];
    #pragma unroll
    for (int j = 0; j < PERK; ++j) hid[j] = sb1[j];
    const float* pp = pooled + (size_t)b * CC * NWIN + w;
    for (int c = 0; c < CC; ++c) {
        float pv = pp[(size_t)c * NWIN];
        #pragma unroll
        for (int j = 0; j < PERK; ++j) hid[j] += pv * sw1[j * CC + c];
    }
    float lg = b2[0];
    #pragma unroll
    for (int j = 0; j < PERK; ++j) {
        float hv = hid[j];
        float g = 0.5f * hv * (1.0f + erff(hv * 0.7071067811865476f));
        lg += g * sw2[j];
    }
    logits[b * NWIN + w] = lg;
}

// -------- k_rankF: fused softmax + stable descending rank (128 blocks x 64) --------
__global__ __launch_bounds__(64) void k_rankF(const float* __restrict__ logits,
        float* __restrict__ probs, float* __restrict__ rw,
        int* __restrict__ rank, int* __restrict__ sel) {
    __shared__ __attribute__((aligned(16))) float sp[NWIN];
    __shared__ float red[64];
    int b = blockIdx.x >> 4, slice = blockIdx.x & 15;
    int tid = threadIdx.x;
    for (int i = tid; i < NWIN / 4; i += 64)
        ((float4*)sp)[i] = ((const float4*)(logits + (size_t)b * NWIN))[i];
    __syncthreads();
    float m = -1e30f;
    for (int i = tid; i < NWIN; i += 64) m = fmaxf(m, sp[i]);
    red[tid] = m; __syncthreads();
    for (int o = 32; o > 0; o >>= 1) { if (tid < o) red[tid] = fmaxf(red[tid], red[tid + o]); __syncthreads(); }
    float mx = red[0]; __syncthreads();
    for (int i = tid; i < NWIN; i += 64) sp[i] = expf(sp[i] - mx);
    __syncthreads();
    float s = 0.f;
    for (int i = tid; i < NWIN; i += 64) s += sp[i];
    red[tid] = s; __syncthreads();
    for (int o = 32; o > 0; o >>= 1) { if (tid < o) red[tid] += red[tid + o]; __syncthreads(); }
    float sum = red[0]; __syncthreads();
    for (int i = tid; i < NWIN; i += 64) sp[i] = sp[i] / sum;
    __syncthreads();
    int w = slice * 64 + tid;
    float p = sp[w];
    probs[b * NWIN + w] = p;
    int r = 0;
    for (int j = 0; j < NWIN; j += 4) {
        float4 pj = *(const float4*)&sp[j];
        r += (int)((pj.x > p) || (pj.x == p && (j + 0) < w));
        r += (int)((pj.y > p) || (pj.y == p && (j + 1) < w));
        r += (int)((pj.z > p) || (pj.z == p && (j + 2) < w));
        r += (int)((pj.w > p) || (pj.w == p && (j + 3) < w));
    }
    rank[b * NWIN + w] = r;
    if (r < TOPK) { sel[b * TOPK + r] = w; rw[b * TOPK + r] = p; }
}

// softplus via hardware exp/log
__device__ __forceinline__ float softplus_f(float v) {
    return fmaxf(v, 0.f) + __logf(1.0f + __expf(-fabsf(v)));
}

// chunk t (= scan-window index) -> selected-window id
__device__ __forceinline__ int window_wsel(const int* sel, int b, int k, int t) {
    int qscan = (k >= 2) ? (255 - t) : t;
    int selidx = (k & 1) ? (((qscan & 15) << 4) | (qscan >> 4)) : qscan;
    return sel[b * TOPK + selidx];
}

// -------- k_gather: scattered x -> dense xs [blk][24][52], barrier-free streaming --------
__global__ __launch_bounds__(256) void k_gather(const float* __restrict__ x,
        const int* __restrict__ sel, float* __restrict__ xsd) {
    const int total = NBK * TCH * XROW;   // 10,223,616
    for (int e = blockIdx.x * 256 + threadIdx.x; e < total; e += gridDim.x * 256) {
        int blk = e / XROW;
        int rem = e - blk * XROW;
        int d2 = rem / LCP, j = rem - d2 * LCP;
        float v = 0.f;
        if (j < 49) {
            int t = blk & 255, bk = blk >> 8, k = bk & 3, b = bk >> 2;
            int wsel = window_wsel(sel, b, k, t);
            int pix = (k >= 2) ? 48 - j : j;
            int q7 = pix / 7, r7 = pix - q7 * 7;
            int wi = (k & 1) ? r7 : q7;
            int wj = (k & 1) ? q7 : r7;
            v = x[(((size_t)b * CC + 4 * d2 + k) * HH + (wsel >> 5) * 7 + wi) * HH
                  + (wsel & 31) * 7 + wj];
        }
        xsd[e] = v;
    }
}

// -------- k_prodT: proj (2-row-paired tasks) -> bf16 stage + f32 carries --------
__global__ __launch_bounds__(384, 4) void k_prodT(
        const float* __restrict__ xsd, const float* __restrict__ wcomb,
        const float* __restrict__ dtb, const float* __restrict__ alogs,
        float* __restrict__ stage, float* __restrict__ carrP, float* __restrict__ carrS) {
    __shared__ __attribute__((aligned(16))) float sxs[PERK][LCP];
    __shared__ __attribute__((aligned(16))) float sprj[56][LCP];  // 0..23 dl, 24..39 B, 40..55 C
    __shared__ float swt[56 * PERK];
    __shared__ float sbias[PERK];
    int blk = blockIdx.x; int k = (blk >> 8) & 3;
    int tid = threadIdx.x;
    const float4* xin = (const float4*)(xsd + (size_t)blk * XROW);
    for (int i = tid; i < XROW / 4; i += 384) ((float4*)sxs)[i] = xin[i];
    for (int i = tid; i < 56 * PERK; i += 384) swt[i] = wcomb[k * (56 * PERK) + i];
    if (tid < PERK) sbias[tid] = dtb[k * PERK + tid];
    if (tid < 168) { int r = tid / 3, j = 49 + tid % 3; sprj[r][j] = 0.f; }
    __syncthreads();
    // projection: 28 row-pairs x 13 groups = 364 tasks, exactly <=1 per thread
    if (tid < 28 * NG) {
        int rp = tid / NG, g = tid - rp * NG; int j = g * 4;
        int row0 = rp * 2, row1 = row0 + 1;
        bool isdl = (row0 < PERK);
        float bs0 = isdl ? sbias[row0] : 0.f;
        float bs1 = isdl ? sbias[row1] : 0.f;
        float a0x = bs0, a0y = bs0, a0z = bs0, a0w = bs0;
        float a1x = bs1, a1y = bs1, a1z = bs1, a1w = bs1;
        #pragma unroll
        for (int d2 = 0; d2 < PERK; ++d2) {
            float w0 = swt[row0 * PERK + d2];
            float w1 = swt[row1 * PERK + d2];
            float4 v = *(const float4*)&sxs[d2][j];
            a0x += w0 * v.x; a0y += w0 * v.y; a0z += w0 * v.z; a0w += w0 * v.w;
            a1x += w1 * v.x; a1y += w1 * v.y; a1z += w1 * v.z; a1w += w1 * v.w;
        }
        if (isdl) {
            a0x = softplus_f(a0x); a0y = softplus_f(a0y); a0z = softplus_f(a0z); a0w = softplus_f(a0w);
            a1x = softplus_f(a1x); a1y = softplus_f(a1y); a1z = softplus_f(a1z); a1w = softplus_f(a1w);
        }
        if (g < 12) {
            float4 o0 = {a0x, a0y, a0z, a0w}; *(float4*)&sprj[row0][j] = o0;
            float4 o1 = {a1x, a1y, a1z, a1w}; *(float4*)&sprj[row1][j] = o1;
        } else {
            sprj[row0][j] = a0x; sprj[row1][j] = a1x;
        }
    }
    __syncthreads();
    // bf16-packed transposed dump: P[13][24] uint4 = (dl,xs)x4 steps; Q[13][16] uint4 = (B,C)x4
    uint4* sgP = (uint4*)(stage + (size_t)blk * WST4);
    uint4* sgQ = sgP + 312;
    for (int tsk = tid; tsk < 312; tsk += 384) {
        int g4 = tsk / 24, d2 = tsk - g4 * 24; int j = g4 * 4;
        uint4 o;
        o.x = pk(sprj[d2][j + 0], sxs[d2][j + 0]);
        o.y = pk(sprj[d2][j + 1], sxs[d2][j + 1]);
        o.z = pk(sprj[d2][j + 2], sxs[d2][j + 2]);
        o.w = pk(sprj[d2][j + 3], sxs[d2][j + 3]);
        sgP[tsk] = o;
    }
    for (int tsk = tid; tsk < 208; tsk += 384) {
        int g4 = tsk / 16, s2 = tsk - g4 * 16; int j = g4 * 4;
        uint4 o;
        o.x = pk(sprj[24 + s2][j + 0], sprj[40 + s2][j + 0]);
        o.y = pk(sprj[24 + s2][j + 1], sprj[40 + s2][j + 1]);
        o.z = pk(sprj[24 + s2][j + 2], sprj[40 + s2][j + 2]);
        o.w = pk(sprj[24 + s2][j + 3], sprj[40 + s2][j + 3]);
        sgQ[tsk] = o;
    }
    // phase-1 carries in f32 (from LDS), exp2-folded with raw v_exp_f32
    int d = tid >> 4, s = tid & 15;
    float A2 = -__expf(alogs[(k * PERK + d) * DST + s]) * LOG2E;
    float P = 1.f, S = 0.f;
    for (int g = 0; g < NG; ++g) {
        int j = g * 4;
        float4 dl4 = *(const float4*)&sprj[d][j];        // pads = 0
        float4 xs4 = *(const float4*)&sxs[d][j];
        float4 B4  = *(const float4*)&sprj[24 + s][j];
        float aa;
        aa = EXP2F(dl4.x * A2); S = aa * S + (dl4.x * xs4.x) * B4.x; P *= aa;
        aa = EXP2F(dl4.y * A2); S = aa * S + (dl4.y * xs4.y) * B4.y; P *= aa;
        aa = EXP2F(dl4.z * A2); S = aa * S + (dl4.z * xs4.z) * B4.z; P *= aa;
        aa = EXP2F(dl4.w * A2); S = aa * S + (dl4.w * xs4.w) * B4.w; P *= aa;
    }
    size_t cidx = (size_t)blk * 384 + tid;
    carrP[cidx] = P; carrS[cidx] = S;
}

// -------- k_cb: blocks [0,48) carry; blocks [48,..) base via LDS transpose --------
// base block = (b, wr, cg of 4 channels): coalesced stripe reads, 784B-contiguous writes
#define RSTR 233       // padded row stride; 233 % 32 = 9 -> ri*9+rj max 2-way bank alias (free)
#define CSTR 1631      // channel stride in buf (7 rows x 233)
__global__ __launch_bounds__(256) void k_cb(const float* carrP, const float* carrS,
        float* hin, const float* __restrict__ x, const float* __restrict__ probs,
        const int* __restrict__ rank, float* __restrict__ out) {
    __shared__ float buf[4 * CSTR];    // 26.1 KB
    __shared__ float fmul[NHW];
    __shared__ int   fsel[NHW];
    if (blockIdx.x < 48) {
        int gid = blockIdx.x * 256 + threadIdx.x;   // 12288
        int bk = gid / 384, ds = gid - bk * 384;
        float Hv = 0.f;
        for (int t = 0; t < TCH; ++t) {
            size_t idx = ((size_t)bk * TCH + t) * 384 + ds;
            float pv = carrP[idx], sv = carrS[idx];
            hin[idx] = Hv;
            Hv = pv * Hv + sv;
        }
        return;
    }
    int bid = blockIdx.x - 48;          // 0..6143
    int cg = bid % 24; int rem = bid / 24;
    int wr = rem % NHW; int b = rem / NHW;
    int tid = threadIdx.x;
    // coalesced stripe load: 4 channels x 7 rows x 224 cols
    for (int i = tid; i < 4 * 7 * 224; i += 256) {
        int ch = i / 1568; int r2 = i - ch * 1568;
        int r = r2 / 224, col = r2 - r * 224;
        buf[ch * CSTR + r * RSTR + col] =
            x[(((size_t)b * CC + cg * 4 + ch) * HH + wr * 7 + r) * HH + col];
    }
    if (tid < NHW) {
        int w = wr * NHW + tid;
        fsel[tid] = (rank[b * NWIN + w] < TOPK);
        fmul[tid] = 1.0f + probs[b * NWIN + w];
    }
    __syncthreads();
    // contiguous writes: per window 4ch x 49 = 196 floats (784 B)
    for (int idx = tid; idx < NHW * 4 * 49; idx += 256) {
        int wc = idx / 196; int r3 = idx - wc * 196;
        if (fsel[wc]) continue;
        int ch = r3 / 49; int rr = r3 - ch * 49;
        int ri = rr / 7, rj = rr - ri * 7;
        float v = buf[ch * CSTR + ri * RSTR + wc * 7 + rj];
        out[(((size_t)b * NWIN + wr * NHW + wc) * CC + cg * 4 + ch) * 49 + rr] = v * fmul[wc];
    }
}

// one recurrence step from packed words: pw=(dl,xs), qw=(B,C); hv = h-chain register
#define BST(hv, widx, pw, qw, jj)                                                  \
    {                                                                              \
        float dl_ = lo_f(pw), xs_ = hi_f(pw), Bv_ = lo_f(qw), Cv_ = hi_f(qw);      \
        float aa_ = EXP2F(dl_ * A2);                                               \
        hv = aa_ * hv + (dl_ * xs_) * Bv_;                                         \
        float part_ = hv * Cv_;                                                    \
        ROR_ADD(part_, 0x121); ROR_ADD(part_, 0x122);                              \
        ROR_ADD(part_, 0x124); ROR_ADD(part_, 0x128);                              \
        if (s == 0 && (jj) < 49) sy[widx][d][jj] = part_ + xs_ * Dsr;              \
    }

// -------- k_scanT: TWO windows per block, interleaved chains; y -> xsd heads --------
__global__ __launch_bounds__(384, 4) void k_scanT(
        const float* __restrict__ alogs, const float* __restrict__ dsv,
        const float* __restrict__ hin, const float* __restrict__ stage,
        float* __restrict__ xsd) {
    __shared__ __attribute__((aligned(16))) float sy[2][PERK][LCP];
    int blk2 = blockIdx.x;                 // 0..4095
    int w0 = blk2 * 2, w1 = w0 + 1;        // same bk (w0 even, 256 windows per bk)
    int k = (w0 >> 8) & 3;
    int tid = threadIdx.x;
    int d = tid >> 4, s = tid & 15;
    float A2 = -__expf(alogs[(k * PERK + d) * DST + s]) * LOG2E;
    float Dsr = dsv[k * PERK + d];
    float h0 = hin[(size_t)w0 * 384 + tid];
    float h1 = hin[(size_t)w1 * 384 + tid];
    const uint4* pP0 = (const uint4*)(stage + (size_t)w0 * WST4) + d;
    const uint4* pQ0 = (const uint4*)(stage + (size_t)w0 * WST4) + 312 + s;
    const uint4* pP1 = (const uint4*)(stage + (size_t)w1 * WST4) + d;
    const uint4* pQ1 = (const uint4*)(stage + (size_t)w1 * WST4) + 312 + s;
    // depth-2 prefetch per window; two independent chains interleaved for ILP
    uint4 P0c = pP0[0],  Q0c = pQ0[0],  P1c = pP1[0],  Q1c = pQ1[0];
    uint4 P0n = pP0[24], Q0n = pQ0[16], P1n = pP1[24], Q1n = pQ1[16];
    for (int g4 = 0; g4 < NG; ++g4) {
        uint4 a0 = P0c, b0 = Q0c, a1 = P1c, b1 = Q1c;
        P0c = P0n; Q0c = Q0n; P1c = P1n; Q1c = Q1n;
        if (g4 + 2 < NG) {
            int jP = (g4 + 2) * 24, jQ = (g4 + 2) * 16;
            P0n = pP0[jP]; Q0n = pQ0[jQ]; P1n = pP1[jP]; Q1n = pQ1[jQ];
        }
        int j = g4 * 4;
        BST(h0, 0, a0.x, b0.x, j);     BST(h1, 1, a1.x, b1.x, j);
        BST(h0, 0, a0.y, b0.y, j + 1); BST(h1, 1, a1.y, b1.y, j + 1);
        BST(h0, 0, a0.z, b0.z, j + 2); BST(h1, 1, a1.z, b1.z, j + 2);
        BST(h0, 0, a0.w, b0.w, j + 3); BST(h1, 1, a1.w, b1.w, j + 3);
    }
    __syncthreads();
    float* y0 = xsd + (size_t)w0 * XROW;
    float* y1 = xsd + (size_t)w1 * XROW;
    for (int idx = tid; idx < PERK * 49; idx += 384) {
        int j = idx / PERK, d2 = idx - j * PERK;
        y0[idx] = sy[0][d2][j];
        y1[idx] = sy[1][d2][j];
    }
}

// -------- k_yadd: selected windows written DIRECTLY: out = x + p*y (no RMW) --------
__global__ __launch_bounds__(256) void k_yadd(const float* __restrict__ ysrc,
        const float* __restrict__ x, const int* __restrict__ sel,
        const float* __restrict__ rw, float* __restrict__ out) {
    __shared__ float ytile[CC * 49];
    int qo = blockIdx.x & 255; int b = blockIdx.x >> 8;
    int wsel = sel[b * TOPK + qo];
    float p = rw[b * TOPK + qo];
    for (int idx = threadIdx.x; idx < CC * 49; idx += 256) {
        int k = idx / 1176; int r1 = idx - k * 1176;
        int u = r1 / 168;   int r2 = r1 - u * 168;
        int wj = r2 / 24;   int d = r2 - wj * 24;
        int rest = qo * 7 + u;
        int b2 = rest & 15; int aw = rest >> 4;
        int wi = aw % 7;    int a = aw / 7;
        int q   = (k & 1) ? (b2 * 16 + a) : (a * 16 + b2);
        int pix = (k & 1) ? (wj * 7 + wi) : (wi * 7 + wj);
        int uu = q * 49 + pix;
        int l = (k >= 2) ? (LL - 1 - uu) : uu;
        int bk = b * 4 + k;
        int t2 = l / 49, jj = l - t2 * 49;
        ytile[(k * PERK + d) * 49 + u * 7 + wj] =
            p * ysrc[((size_t)(bk * 256 + t2)) * XROW + jj * PERK + d];
    }
    __syncthreads();
    float* ob = out + ((size_t)(b * NWIN + wsel) * CC) * 49;
    int gi0 = (wsel >> 5) * 7, gj0 = (wsel & 31) * 7;
    for (int e = threadIdx.x; e < CC * 49; e += 256) {
        int C = e / 49, cell = e - C * 49;
        int u = cell / 7, wj = cell - u * 7;
        float xv = x[(((size_t)b * CC + C) * HH + gi0 + u) * HH + gj0 + wj];
        ob[e] = xv + ytile[e];
    }
}

extern "C" void kernel_launch(void* const* d_in, const int* in_sizes, int n_in,
                              void* d_out, int out_size, void* d_ws, size_t ws_size,
                              hipStream_t stream) {
    const float* x   = (const float*)d_in[0];
    const float* w1  = (const float*)d_in[1];
    const float* b1  = (const float*)d_in[2];
    const float* w2  = (const float*)d_in[3];
    const float* b2  = (const float*)d_in[4];
    const float* xpw = (const float*)d_in[5];
    const float* dtw = (const float*)d_in[6];
    const float* dtb = (const float*)d_in[7];
    const float* alg = (const float*)d_in[8];
    const float* dsv = (const float*)d_in[9];
    float* out = (float*)d_out;
    float* ws  = (float*)d_ws;

    float* pooled = ws + OFF_POOL;
    float* logits = ws + OFF_LOG;
    float* probs  = ws + OFF_PROB;
    float* rwv    = ws + OFF_RW;
    int*   rank   = (int*)(ws + OFF_RANK);
    int*   sel    = (int*)(ws + OFF_SEL);
    float* wcomb  = ws + OFF_WEFF;
    float* cP  = ws + OFF_CP;       // also hin after carry
    float* cS  = ws + OFF_CS;
    float* xsd = ws + OFF_XSD;      // xs dense; y written into head by k_scanT
    float* stage = ws + OFF_STG;

    k_pool  <<<BBATCH * CC, 256, 0, stream>>>(x, pooled);
    k_router<<<BBATCH * 16, 64, 0, stream>>>(pooled, w1, b1, w2, b2, xpw, dtw, wcomb, logits);
    k_rankF <<<BBATCH * 16, 64, 0, stream>>>(logits, probs, rwv, rank, sel);
    k_gather<<<2048, 256, 0, stream>>>(x, sel, xsd);
    k_prodT <<<NBK * TCH, 384, 0, stream>>>(xsd, wcomb, dtb, alg, stage, cP, cS);
    k_cb    <<<48 + BBATCH * NHW * 24, 256, 0, stream>>>(cP, cS, cP, x, probs, rank, out);
    k_scanT <<<NBK * TCH / 2, 384, 0, stream>>>(alg, dsv, cP, stage, xsd);
    k_yadd  <<<BBATCH * TOPK, 256, 0, stream>>>(xsd, x, sel, rwv, out);
}

// Round 21
// 407.583 us; speedup vs baseline: 1.2082x; 1.0471x over previous
//
#include <hip/hip_runtime.h>
#include <math.h>

// Problem constants
#define BBATCH 8
#define CC 96
#define HH 224
#define NHW 32            // 224/7 windows per side
#define NWIN 1024
#define TOPK 256
#define PERK 24
#define DST 16
#define DTR 6
#define LL 12544          // 256*49
#define LCP 52            // padded row length (49 used + 3 zero pad)
#define NG 13             // float4 groups per row
#define TCH 256           // one chunk = ONE scan window (49 steps)
#define NBK 32            // B*4 directions
#define XROW 1248         // xs floats per window: 24 x 52 (y reuses head: 1176)
#define WST4 2080         // bf16 stage floats per window: P 312 uint4 + Q 208 uint4
#define LOG2E 1.4426950408889634f

// fast hardware exp2: exactly one v_exp_f32
#define EXP2F(x) __builtin_amdgcn_exp2f(x)

// workspace offsets (floats) — total 34,374,912 floats = 137.5 MB (< proven 164.8)
#define OFF_POOL 0
#define OFF_LOG  786432
#define OFF_PROB 794624
#define OFF_RW   802816
#define OFF_RANK 804864
#define OFF_SEL  813056
#define OFF_WEFF 815104
#define OFF_CP   820480      // 3,145,728; reused as hin (read-before-write in carry)
#define OFF_CS   3966208     // 3,145,728
#define OFF_XSD  7111936     // 10,223,616: xs dense [8192][24][52]; y written into head
#define OFF_STG  17335552    // 8192*2080 = 17,039,360: bf16-packed stage

// DPP row_ror:N add — 16-lane full-sum reduction on the VALU pipe (not DS)
#define ROR_ADD(v, CTRL) \
    v += __int_as_float(__builtin_amdgcn_update_dpp(0, __float_as_int(v), CTRL, 0xf, 0xf, true))

// f32 -> bf16 (RNE) and packing helpers
__device__ __forceinline__ unsigned f2b(float f) {
    unsigned u = __float_as_uint(f);
    return (u + 0x7fffu + ((u >> 16) & 1u)) >> 16;
}
__device__ __forceinline__ unsigned pk(float a, float b) {   // a -> low16, b -> high16
    return f2b(a) | (f2b(b) << 16);
}
__device__ __forceinline__ float lo_f(unsigned w) { return __uint_as_float(w << 16); }
__device__ __forceinline__ float hi_f(unsigned w) { return __uint_as_float(w & 0xffff0000u); }

// -------- k_pool: window pooling: pooledT[b][c][w] --------
__global__ void k_pool(const float* __restrict__ x, float* __restrict__ pooled) {
    int bc = blockIdx.x;                 // b*96+c
    const float* xp = x + (size_t)bc * HH * HH;
    float* pp = pooled + (size_t)bc * NWIN;
    for (int w = threadIdx.x; w < NWIN; w += blockDim.x) {
        int wr = w >> 5, wc = w & 31;
        const float* base = xp + (wr * 7) * HH + wc * 7;
        float s = 0.f;
        #pragma unroll
        for (int i = 0; i < 7; ++i) {
            #pragma unroll
            for (int j = 0; j < 7; ++j) s += base[i * HH + j];
        }
        pp[w] = s * (1.0f / 49.0f);
    }
}

// -------- k_router: MLP logits (128 blocks x 64) + weff fold (striped) --------
__global__ __launch_bounds__(64) void k_router(
        const float* __restrict__ pooled,
        const float* __restrict__ w1, const float* __restrict__ b1,
        const float* __restrict__ w2, const float* __restrict__ b2,
        const float* __restrict__ xpw, const float* __restrict__ dtw,
        float* __restrict__ wcomb, float* __restrict__ logits) {
    __shared__ float sw1[PERK * CC];
    __shared__ float sb1[PERK];
    __shared__ float sw2[PERK];
    int b = blockIdx.x >> 4, slice = blockIdx.x & 15;
    int tid = threadIdx.x;
    // ---- weff slice: Wcomb[k][56][24] (used later by k_prodT only) ----
    for (int i = blockIdx.x * 64 + tid; i < 4 * 56 * PERK; i += 128 * 64) {
        int k = i / (56 * PERK), rem = i - k * (56 * PERK);
        int row = rem / PERK, c = rem - row * PERK;
        float v;
        if (row < PERK) {
            v = 0.f;
            #pragma unroll
            for (int r = 0; r < DTR; ++r)
                v += dtw[(k * PERK + row) * DTR + r] * xpw[(k * 38 + r) * PERK + c];
        } else {
            v = xpw[(k * 38 + (row - PERK + DTR)) * PERK + c];
        }
        wcomb[i] = v;
    }
    // ---- router ----
    for (int i = tid; i < PERK * CC; i += 64) sw1[i] = w1[i];
    if (tid < PERK) { sb1[tid] = b1[tid]; sw2[tid] = w2[tid]; }
    __syncthreads();
    int w = slice * 64 + tid;
    float hid[PERK];
    #pragma unroll
    for (int j = 0; j < PERK; ++j) hid[j] = sb1[j];
    const float* pp = pooled + (size_t)b * CC * NWIN + w;
    for (int c = 0; c < CC; ++c) {
        float pv = pp[(size_t)c * NWIN];
        #pragma unroll
        for (int j = 0; j < PERK; ++j) hid[j] += pv * sw1[j * CC + c];
    }
    float lg = b2[0];
    #pragma unroll
    for (int j = 0; j < PERK; ++j) {
        float hv = hid[j];
        float g = 0.5f * hv * (1.0f + erff(hv * 0.7071067811865476f));
        lg += g * sw2[j];
    }
    logits[b * NWIN + w] = lg;
}

// -------- k_rankF: fused softmax + stable descending rank (128 blocks x 64) --------
__global__ __launch_bounds__(64) void k_rankF(const float* __restrict__ logits,
        float* __restrict__ probs, float* __restrict__ rw,
        int* __restrict__ rank, int* __restrict__ sel) {
    __shared__ __attribute__((aligned(16))) float sp[NWIN];
    __shared__ float red[64];
    int b = blockIdx.x >> 4, slice = blockIdx.x & 15;
    int tid = threadIdx.x;
    for (int i = tid; i < NWIN / 4; i += 64)
        ((float4*)sp)[i] = ((const float4*)(logits + (size_t)b * NWIN))[i];
    __syncthreads();
    float m = -1e30f;
    for (int i = tid; i < NWIN; i += 64) m = fmaxf(m, sp[i]);
    red[tid] = m; __syncthreads();
    for (int o = 32; o > 0; o >>= 1) { if (tid < o) red[tid] = fmaxf(red[tid], red[tid + o]); __syncthreads(); }
    float mx = red[0]; __syncthreads();
    for (int i = tid; i < NWIN; i += 64) sp[i] = expf(sp[i] - mx);
    __syncthreads();
    float s = 0.f;
    for (int i = tid; i < NWIN; i += 64) s += sp[i];
    red[tid] = s; __syncthreads();
    for (int o = 32; o > 0; o >>= 1) { if (tid < o) red[tid] += red[tid + o]; __syncthreads(); }
    float sum = red[0]; __syncthreads();
    for (int i = tid; i < NWIN; i += 64) sp[i] = sp[i] / sum;
    __syncthreads();
    int w = slice * 64 + tid;
    float p = sp[w];
    probs[b * NWIN + w] = p;
    int r = 0;
    for (int j = 0; j < NWIN; j += 4) {
        float4 pj = *(const float4*)&sp[j];
        r += (int)((pj.x > p) || (pj.x == p && (j + 0) < w));
        r += (int)((pj.y > p) || (pj.y == p && (j + 1) < w));
        r += (int)((pj.z > p) || (pj.z == p && (j + 2) < w));
        r += (int)((pj.w > p) || (pj.w == p && (j + 3) < w));
    }
    rank[b * NWIN + w] = r;
    if (r < TOPK) { sel[b * TOPK + r] = w; rw[b * TOPK + r] = p; }
}

// softplus via hardware exp/log
__device__ __forceinline__ float softplus_f(float v) {
    return fmaxf(v, 0.f) + __logf(1.0f + __expf(-fabsf(v)));
}

// chunk t (= scan-window index) -> selected-window id
__device__ __forceinline__ int window_wsel(const int* sel, int b, int k, int t) {
    int qscan = (k >= 2) ? (255 - t) : t;
    int selidx = (k & 1) ? (((qscan & 15) << 4) | (qscan >> 4)) : qscan;
    return sel[b * TOPK + selidx];
}

// -------- k_gather: scattered x -> dense xs [blk][24][52], barrier-free streaming --------
__global__ __launch_bounds__(256) void k_gather(const float* __restrict__ x,
        const int* __restrict__ sel, float* __restrict__ xsd) {
    const int total = NBK * TCH * XROW;   // 10,223,616
    for (int e = blockIdx.x * 256 + threadIdx.x; e < total; e += gridDim.x * 256) {
        int blk = e / XROW;
        int rem = e - blk * XROW;
        int d2 = rem / LCP, j = rem - d2 * LCP;
        float v = 0.f;
        if (j < 49) {
            int t = blk & 255, bk = blk >> 8, k = bk & 3, b = bk >> 2;
            int wsel = window_wsel(sel, b, k, t);
            int pix = (k >= 2) ? 48 - j : j;
            int q7 = pix / 7, r7 = pix - q7 * 7;
            int wi = (k & 1) ? r7 : q7;
            int wj = (k & 1) ? q7 : r7;
            v = x[(((size_t)b * CC + 4 * d2 + k) * HH + (wsel >> 5) * 7 + wi) * HH
                  + (wsel & 31) * 7 + wj];
        }
        xsd[e] = v;
    }
}

// -------- k_prodT: proj (2-row-paired tasks) -> bf16 stage + f32 carries --------
__global__ __launch_bounds__(384, 4) void k_prodT(
        const float* __restrict__ xsd, const float* __restrict__ wcomb,
        const float* __restrict__ dtb, const float* __restrict__ alogs,
        float* __restrict__ stage, float* __restrict__ carrP, float* __restrict__ carrS) {
    __shared__ __attribute__((aligned(16))) float sxs[PERK][LCP];
    __shared__ __attribute__((aligned(16))) float sprj[56][LCP];  // 0..23 dl, 24..39 B, 40..55 C
    __shared__ float swt[56 * PERK];
    __shared__ float sbias[PERK];
    int blk = blockIdx.x; int k = (blk >> 8) & 3;
    int tid = threadIdx.x;
    const float4* xin = (const float4*)(xsd + (size_t)blk * XROW);
    for (int i = tid; i < XROW / 4; i += 384) ((float4*)sxs)[i] = xin[i];
    for (int i = tid; i < 56 * PERK; i += 384) swt[i] = wcomb[k * (56 * PERK) + i];
    if (tid < PERK) sbias[tid] = dtb[k * PERK + tid];
    if (tid < 168) { int r = tid / 3, j = 49 + tid % 3; sprj[r][j] = 0.f; }
    __syncthreads();
    // projection: 28 row-pairs x 13 groups = 364 tasks, exactly <=1 per thread
    if (tid < 28 * NG) {
        int rp = tid / NG, g = tid - rp * NG; int j = g * 4;
        int row0 = rp * 2, row1 = row0 + 1;
        bool isdl = (row0 < PERK);
        float bs0 = isdl ? sbias[row0] : 0.f;
        float bs1 = isdl ? sbias[row1] : 0.f;
        float a0x = bs0, a0y = bs0, a0z = bs0, a0w = bs0;
        float a1x = bs1, a1y = bs1, a1z = bs1, a1w = bs1;
        #pragma unroll
        for (int d2 = 0; d2 < PERK; ++d2) {
            float w0 = swt[row0 * PERK + d2];
            float w1 = swt[row1 * PERK + d2];
            float4 v = *(const float4*)&sxs[d2][j];
            a0x += w0 * v.x; a0y += w0 * v.y; a0z += w0 * v.z; a0w += w0 * v.w;
            a1x += w1 * v.x; a1y += w1 * v.y; a1z += w1 * v.z; a1w += w1 * v.w;
        }
        if (isdl) {
            a0x = softplus_f(a0x); a0y = softplus_f(a0y); a0z = softplus_f(a0z); a0w = softplus_f(a0w);
            a1x = softplus_f(a1x); a1y = softplus_f(a1y); a1z = softplus_f(a1z); a1w = softplus_f(a1w);
        }
        if (g < 12) {
            float4 o0 = {a0x, a0y, a0z, a0w}; *(float4*)&sprj[row0][j] = o0;
            float4 o1 = {a1x, a1y, a1z, a1w}; *(float4*)&sprj[row1][j] = o1;
        } else {
            sprj[row0][j] = a0x; sprj[row1][j] = a1x;
        }
    }
    __syncthreads();
    // bf16-packed transposed dump: P[13][24] uint4 = (dl,xs)x4 steps; Q[13][16] uint4 = (B,C)x4
    uint4* sgP = (uint4*)(stage + (size_t)blk * WST4);
    uint4* sgQ = sgP + 312;
    for (int tsk = tid; tsk < 312; tsk += 384) {
        int g4 = tsk / 24, d2 = tsk - g4 * 24; int j = g4 * 4;
        uint4 o;
        o.x = pk(sprj[d2][j + 0], sxs[d2][j + 0]);
        o.y = pk(sprj[d2][j + 1], sxs[d2][j + 1]);
        o.z = pk(sprj[d2][j + 2], sxs[d2][j + 2]);
        o.w = pk(sprj[d2][j + 3], sxs[d2][j + 3]);
        sgP[tsk] = o;
    }
    for (int tsk = tid; tsk < 208; tsk += 384) {
        int g4 = tsk / 16, s2 = tsk - g4 * 16; int j = g4 * 4;
        uint4 o;
        o.x = pk(sprj[24 + s2][j + 0], sprj[40 + s2][j + 0]);
        o.y = pk(sprj[24 + s2][j + 1], sprj[40 + s2][j + 1]);
        o.z = pk(sprj[24 + s2][j + 2], sprj[40 + s2][j + 2]);
        o.w = pk(sprj[24 + s2][j + 3], sprj[40 + s2][j + 3]);
        sgQ[tsk] = o;
    }
    // phase-1 carries in f32 (from LDS), exp2-folded with raw v_exp_f32
    int d = tid >> 4, s = tid & 15;
    float A2 = -__expf(alogs[(k * PERK + d) * DST + s]) * LOG2E;
    float P = 1.f, S = 0.f;
    for (int g = 0; g < NG; ++g) {
        int j = g * 4;
        float4 dl4 = *(const float4*)&sprj[d][j];        // pads = 0
        float4 xs4 = *(const float4*)&sxs[d][j];
        float4 B4  = *(const float4*)&sprj[24 + s][j];
        float aa;
        aa = EXP2F(dl4.x * A2); S = aa * S + (dl4.x * xs4.x) * B4.x; P *= aa;
        aa = EXP2F(dl4.y * A2); S = aa * S + (dl4.y * xs4.y) * B4.y; P *= aa;
        aa = EXP2F(dl4.z * A2); S = aa * S + (dl4.z * xs4.z) * B4.z; P *= aa;
        aa = EXP2F(dl4.w * A2); S = aa * S + (dl4.w * xs4.w) * B4.w; P *= aa;
    }
    size_t cidx = (size_t)blk * 384 + tid;
    carrP[cidx] = P; carrS[cidx] = S;
}

// -------- k_cb: blocks [0,48) pipelined carry; blocks [48,..) base via LDS transpose --------
// base block = (b, wr, cg of 4 channels): coalesced stripe reads, 784B-contiguous writes
#define RSTR 233       // padded row stride; 233 % 32 = 9 -> ri*9+rj max 2-way bank alias (free)
#define CSTR 1631      // channel stride in buf (7 rows x 233)
__global__ __launch_bounds__(256) void k_cb(const float* carrP, const float* carrS,
        float* hin, const float* __restrict__ x, const float* __restrict__ probs,
        const int* __restrict__ rank, float* __restrict__ out) {
    __shared__ float buf[4 * CSTR];    // 26.1 KB
    __shared__ float fmul[NHW];
    __shared__ int   fsel[NHW];
    if (blockIdx.x < 48) {
        // carry: 256-step chain, groups of 4 with depth-3 prefetch (24 loads in flight)
        int gid = blockIdx.x * 256 + threadIdx.x;   // 12288
        int bk = gid / 384, ds = gid - bk * 384;
        const float* pP = carrP + (size_t)bk * TCH * 384 + ds;
        const float* pS = carrS + (size_t)bk * TCH * 384 + ds;
        float* pH = hin + (size_t)bk * TCH * 384 + ds;
        float Hv = 0.f;
        float g0p0, g0p1, g0p2, g0p3, g0s0, g0s1, g0s2, g0s3;
        float g1p0, g1p1, g1p2, g1p3, g1s0, g1s1, g1s2, g1s3;
        float g2p0, g2p1, g2p2, g2p3, g2s0, g2s1, g2s2, g2s3;
        #define CLD(base, P0, P1, P2, P3, S0, S1, S2, S3)                      \
            P0 = pP[(base) * 384];       P1 = pP[((base) + 1) * 384];          \
            P2 = pP[((base) + 2) * 384]; P3 = pP[((base) + 3) * 384];          \
            S0 = pS[(base) * 384];       S1 = pS[((base) + 1) * 384];          \
            S2 = pS[((base) + 2) * 384]; S3 = pS[((base) + 3) * 384];
        CLD(0, g0p0, g0p1, g0p2, g0p3, g0s0, g0s1, g0s2, g0s3);
        CLD(4, g1p0, g1p1, g1p2, g1p3, g1s0, g1s1, g1s2, g1s3);
        CLD(8, g2p0, g2p1, g2p2, g2p3, g2s0, g2s1, g2s2, g2s3);
        for (int g = 0; g < 64; ++g) {
            int t = g * 4;
            pH[(t + 0) * 384] = Hv; Hv = g0p0 * Hv + g0s0;
            pH[(t + 1) * 384] = Hv; Hv = g0p1 * Hv + g0s1;
            pH[(t + 2) * 384] = Hv; Hv = g0p2 * Hv + g0s2;
            pH[(t + 3) * 384] = Hv; Hv = g0p3 * Hv + g0s3;
            g0p0 = g1p0; g0p1 = g1p1; g0p2 = g1p2; g0p3 = g1p3;
            g0s0 = g1s0; g0s1 = g1s1; g0s2 = g1s2; g0s3 = g1s3;
            g1p0 = g2p0; g1p1 = g2p1; g1p2 = g2p2; g1p3 = g2p3;
            g1s0 = g2s0; g1s1 = g2s1; g1s2 = g2s2; g1s3 = g2s3;
            if (g + 3 < 64) {
                CLD((g + 3) * 4, g2p0, g2p1, g2p2, g2p3, g2s0, g2s1, g2s2, g2s3);
            }
        }
        return;
    }
    int bid = blockIdx.x - 48;          // 0..6143
    int cg = bid % 24; int rem = bid / 24;
    int wr = rem % NHW; int b = rem / NHW;
    int tid = threadIdx.x;
    // coalesced stripe load: 4 channels x 7 rows x 224 cols
    for (int i = tid; i < 4 * 7 * 224; i += 256) {
        int ch = i / 1568; int r2 = i - ch * 1568;
        int r = r2 / 224, col = r2 - r * 224;
        buf[ch * CSTR + r * RSTR + col] =
            x[(((size_t)b * CC + cg * 4 + ch) * HH + wr * 7 + r) * HH + col];
    }
    if (tid < NHW) {
        int w = wr * NHW + tid;
        fsel[tid] = (rank[b * NWIN + w] < TOPK);
        fmul[tid] = 1.0f + probs[b * NWIN + w];
    }
    __syncthreads();
    // contiguous writes: per window 4ch x 49 = 196 floats (784 B)
    for (int idx = tid; idx < NHW * 4 * 49; idx += 256) {
        int wc = idx / 196; int r3 = idx - wc * 196;
        if (fsel[wc]) continue;
        int ch = r3 / 49; int rr = r3 - ch * 49;
        int ri = rr / 7, rj = rr - ri * 7;
        float v = buf[ch * CSTR + ri * RSTR + wc * 7 + rj];
        out[(((size_t)b * NWIN + wr * NHW + wc) * CC + cg * 4 + ch) * 49 + rr] = v * fmul[wc];
    }
}

// one recurrence step from packed words: pw=(dl,xs), qw=(B,C); hv = h-chain register
#define BST(hv, widx, pw, qw, jj)                                                  \
    {                                                                              \
        float dl_ = lo_f(pw), xs_ = hi_f(pw), Bv_ = lo_f(qw), Cv_ = hi_f(qw);      \
        float aa_ = EXP2F(dl_ * A2);                                               \
        hv = aa_ * hv + (dl_ * xs_) * Bv_;                                         \
        float part_ = hv * Cv_;                                                    \
        ROR_ADD(part_, 0x121); ROR_ADD(part_, 0x122);                              \
        ROR_ADD(part_, 0x124); ROR_ADD(part_, 0x128);                              \
        if (s == 0 && (jj) < 49) sy[widx][d][jj] = part_ + xs_ * Dsr;              \
    }

// -------- k_scanT: TWO windows per block, interleaved chains; y -> xsd heads --------
__global__ __launch_bounds__(384, 4) void k_scanT(
        const float* __restrict__ alogs, const float* __restrict__ dsv,
        const float* __restrict__ hin, const float* __restrict__ stage,
        float* __restrict__ xsd) {
    __shared__ __attribute__((aligned(16))) float sy[2][PERK][LCP];
    int blk2 = blockIdx.x;                 // 0..4095
    int w0 = blk2 * 2, w1 = w0 + 1;        // same bk (w0 even, 256 windows per bk)
    int k = (w0 >> 8) & 3;
    int tid = threadIdx.x;
    int d = tid >> 4, s = tid & 15;
    float A2 = -__expf(alogs[(k * PERK + d) * DST + s]) * LOG2E;
    float Dsr = dsv[k * PERK + d];
    float h0 = hin[(size_t)w0 * 384 + tid];
    float h1 = hin[(size_t)w1 * 384 + tid];
    const uint4* pP0 = (const uint4*)(stage + (size_t)w0 * WST4) + d;
    const uint4* pQ0 = (const uint4*)(stage + (size_t)w0 * WST4) + 312 + s;
    const uint4* pP1 = (const uint4*)(stage + (size_t)w1 * WST4) + d;
    const uint4* pQ1 = (const uint4*)(stage + (size_t)w1 * WST4) + 312 + s;
    // depth-2 prefetch per window; two independent chains interleaved for ILP
    uint4 P0c = pP0[0],  Q0c = pQ0[0],  P1c = pP1[0],  Q1c = pQ1[0];
    uint4 P0n = pP0[24], Q0n = pQ0[16], P1n = pP1[24], Q1n = pQ1[16];
    for (int g4 = 0; g4 < NG; ++g4) {
        uint4 a0 = P0c, b0 = Q0c, a1 = P1c, b1 = Q1c;
        P0c = P0n; Q0c = Q0n; P1c = P1n; Q1c = Q1n;
        if (g4 + 2 < NG) {
            int jP = (g4 + 2) * 24, jQ = (g4 + 2) * 16;
            P0n = pP0[jP]; Q0n = pQ0[jQ]; P1n = pP1[jP]; Q1n = pQ1[jQ];
        }
        int j = g4 * 4;
        BST(h0, 0, a0.x, b0.x, j);     BST(h1, 1, a1.x, b1.x, j);
        BST(h0, 0, a0.y, b0.y, j + 1); BST(h1, 1, a1.y, b1.y, j + 1);
        BST(h0, 0, a0.z, b0.z, j + 2); BST(h1, 1, a1.z, b1.z, j + 2);
        BST(h0, 0, a0.w, b0.w, j + 3); BST(h1, 1, a1.w, b1.w, j + 3);
    }
    __syncthreads();
    float* y0 = xsd + (size_t)w0 * XROW;
    float* y1 = xsd + (size_t)w1 * XROW;
    for (int idx = tid; idx < PERK * 49; idx += 384) {
        int j = idx / PERK, d2 = idx - j * PERK;
        y0[idx] = sy[0][d2][j];
        y1[idx] = sy[1][d2][j];
    }
}

// -------- k_yadd: selected windows written DIRECTLY: out = x + p*y (no RMW) --------
__global__ __launch_bounds__(256) void k_yadd(const float* __restrict__ ysrc,
        const float* __restrict__ x, const int* __restrict__ sel,
        const float* __restrict__ rw, float* __restrict__ out) {
    __shared__ float ytile[CC * 49];
    int qo = blockIdx.x & 255; int b = blockIdx.x >> 8;
    int wsel = sel[b * TOPK + qo];
    float p = rw[b * TOPK + qo];
    for (int idx = threadIdx.x; idx < CC * 49; idx += 256) {
        int k = idx / 1176; int r1 = idx - k * 1176;
        int u = r1 / 168;   int r2 = r1 - u * 168;
        int wj = r2 / 24;   int d = r2 - wj * 24;
        int rest = qo * 7 + u;
        int b2 = rest & 15; int aw = rest >> 4;
        int wi = aw % 7;    int a = aw / 7;
        int q   = (k & 1) ? (b2 * 16 + a) : (a * 16 + b2);
        int pix = (k & 1) ? (wj * 7 + wi) : (wi * 7 + wj);
        int uu = q * 49 + pix;
        int l = (k >= 2) ? (LL - 1 - uu) : uu;
        int bk = b * 4 + k;
        int t2 = l / 49, jj = l - t2 * 49;
        ytile[(k * PERK + d) * 49 + u * 7 + wj] =
            p * ysrc[((size_t)(bk * 256 + t2)) * XROW + jj * PERK + d];
    }
    __syncthreads();
    float* ob = out + ((size_t)(b * NWIN + wsel) * CC) * 49;
    int gi0 = (wsel >> 5) * 7, gj0 = (wsel & 31) * 7;
    for (int e = threadIdx.x; e < CC * 49; e += 256) {
        int C = e / 49, cell = e - C * 49;
        int u = cell / 7, wj = cell - u * 7;
        float xv = x[(((size_t)b * CC + C) * HH + gi0 + u) * HH + gj0 + wj];
        ob[e] = xv + ytile[e];
    }
}

extern "C" void kernel_launch(void* const* d_in, const int* in_sizes, int n_in,
                              void* d_out, int out_size, void* d_ws, size_t ws_size,
                              hipStream_t stream) {
    const float* x   = (const float*)d_in[0];
    const float* w1  = (const float*)d_in[1];
    const float* b1  = (const float*)d_in[2];
    const float* w2  = (const float*)d_in[3];
    const float* b2  = (const float*)d_in[4];
    const float* xpw = (const float*)d_in[5];
    const float* dtw = (const float*)d_in[6];
    const float* dtb = (const float*)d_in[7];
    const float* alg = (const float*)d_in[8];
    const float* dsv = (const float*)d_in[9];
    float* out = (float*)d_out;
    float* ws  = (float*)d_ws;

    float* pooled = ws + OFF_POOL;
    float* logits = ws + OFF_LOG;
    float* probs  = ws + OFF_PROB;
    float* rwv    = ws + OFF_RW;
    int*   rank   = (int*)(ws + OFF_RANK);
    int*   sel    = (int*)(ws + OFF_SEL);
    float* wcomb  = ws + OFF_WEFF;
    float* cP  = ws + OFF_CP;       // also hin after carry
    float* cS  = ws + OFF_CS;
    float* xsd = ws + OFF_XSD;      // xs dense; y written into head by k_scanT
    float* stage = ws + OFF_STG;

    k_pool  <<<BBATCH * CC, 256, 0, stream>>>(x, pooled);
    k_router<<<BBATCH * 16, 64, 0, stream>>>(pooled, w1, b1, w2, b2, xpw, dtw, wcomb, logits);
    k_rankF <<<BBATCH * 16, 64, 0, stream>>>(logits, probs, rwv, rank, sel);
    k_gather<<<2048, 256, 0, stream>>>(x, sel, xsd);
    k_prodT <<<NBK * TCH, 384, 0, stream>>>(xsd, wcomb, dtb, alg, stage, cP, cS);
    k_cb    <<<48 + BBATCH * NHW * 24, 256, 0, stream>>>(cP, cS, cP, x, probs, rank, out);
    k_scanT <<<NBK * TCH / 2, 384, 0, stream>>>(alg, dsv, cP, stage, xsd);
    k_yadd  <<<BBATCH * TOPK, 256, 0, stream>>>(xsd, x, sel, rwv, out);
}